// Round 12
// baseline (140.018 us; speedup 1.0000x reference)
//
#include <hip/hip_runtime.h>
#include <hip/hip_bf16.h>
#include <stdint.h>

#define NB 8
#define DIMG 2048
#define HWN 196
#define PN 1568
#define DMID 1024
#define NC 80
#define DWORD 300
#define PART 4

typedef short bf16x8 __attribute__((ext_vector_type(8)));
typedef float f32x4 __attribute__((ext_vector_type(4)));

__device__ __forceinline__ unsigned short f2bf(float x) {
  union { float f; unsigned u; } c; c.f = x;
  unsigned r = c.u + 0x7FFFu + ((c.u >> 16) & 1u);
  return (unsigned short)(r >> 16);
}
__device__ __forceinline__ float bflo(unsigned u) {
  union { unsigned v; float f; } c; c.v = u << 16; return c.f;
}
__device__ __forceinline__ float bfhi(unsigned u) {
  union { unsigned v; float f; } c; c.v = u & 0xffff0000u; return c.f;
}

// ---------------------------------------------------------------- transpose (bf16 only) + W1 cvt
__global__ void k_tc(const float* __restrict__ img, unsigned short* __restrict__ fmapH,
                     const float* __restrict__ W1, unsigned short* __restrict__ W1h) {
  __shared__ float tile[32][33];
  int bx = blockIdx.x;
  int tx = threadIdx.x, ty = threadIdx.y;
  if (bx < 3584) {
    int d0 = (bx & 63) * 32;
    int rem = bx >> 6;
    int h0 = (rem % 7) * 32, b = rem / 7;
    const float* src = img + (size_t)b * DIMG * HWN;
#pragma unroll
    for (int i = 0; i < 32; i += 8) {
      int hw = h0 + tx;
      tile[ty + i][tx] = (hw < HWN) ? src[(size_t)(d0 + ty + i) * HWN + hw] : 0.f;
    }
    __syncthreads();
#pragma unroll
    for (int i = 0; i < 32; i += 8) {
      int hw = h0 + ty + i;
      if (hw < HWN)
        fmapH[(size_t)(b * HWN + hw) * DIMG + d0 + tx] = f2bf(tile[tx][ty + i]);
    }
  } else {
    int tid = ty * 32 + tx;
    int i = ((bx - 3584) * 256 + tid) * 4;
    f32x4 v = *(const f32x4*)(W1 + i);
    ushort4 s;
    s.x = f2bf(v[0]); s.y = f2bf(v[1]); s.z = f2bf(v[2]); s.w = f2bf(v[3]);
    *(ushort4*)(W1h + i) = s;
  }
}

// ---------------------------------------------------------------- fwd + weff (coalesced, LDS-staged)
// fwd[c][m] = SC * sum_k word[c][k]*W2[m][k]  (SC = 2*log2e)
__global__ __launch_bounds__(256) void k_fwdweff(const float* __restrict__ word,
                                                 const float* __restrict__ W2,
                                                 float* __restrict__ fwd,
                                                 const float* __restrict__ Wa,
                                                 const float* __restrict__ W3,
                                                 float* __restrict__ partial) {
  __shared__ __align__(16) float w2s[64 * DWORD];   // 76.8 KB
  __shared__ __align__(16) float wds[16 * DWORD];   // 19.2 KB
  int bx = blockIdx.x, t = threadIdx.x;
  if (bx < 80) {
    int m0 = (bx & 15) * 64, c0 = (bx >> 4) * 16;
    const float SC = 2.8853900817779268f;  // 2*log2(e)
    for (int u = t; u < 64 * 75; u += 256) {
      int r = u / 75, q = u - r * 75;
      *(f32x4*)&w2s[r * DWORD + q * 4] =
          *(const f32x4*)(W2 + (size_t)(m0 + r) * DWORD + q * 4);
    }
    for (int u = t; u < 16 * 75; u += 256) {
      int r = u / 75, q = u - r * 75;
      f32x4 v = *(const f32x4*)(word + (size_t)(c0 + r) * DWORD + q * 4);
      *(f32x4*)&wds[r * DWORD + q * 4] = v * SC;
    }
    __syncthreads();
    int ci = t >> 4, mi = t & 15;
    f32x4 a0 = {0.f, 0.f, 0.f, 0.f}, a1 = a0, a2 = a0, a3 = a0;
    const float* wr = &wds[ci * DWORD];
    for (int q = 0; q < 75; ++q) {
      f32x4 wv = *(const f32x4*)&wr[q * 4];
      f32x4 b0 = *(const f32x4*)&w2s[(mi)*DWORD + q * 4];
      f32x4 b1 = *(const f32x4*)&w2s[(mi + 16) * DWORD + q * 4];
      f32x4 b2 = *(const f32x4*)&w2s[(mi + 32) * DWORD + q * 4];
      f32x4 b3 = *(const f32x4*)&w2s[(mi + 48) * DWORD + q * 4];
#pragma unroll
      for (int u = 0; u < 4; ++u) {
        a0[u] = fmaf(wv[u], b0[u], a0[u]);
        a1[u] = fmaf(wv[u], b1[u], a1[u]);
        a2[u] = fmaf(wv[u], b2[u], a2[u]);
        a3[u] = fmaf(wv[u], b3[u], a3[u]);
      }
    }
    float* dst = fwd + (size_t)(c0 + ci) * DMID + m0 + mi;
    dst[0]  = a0[0] + a0[1] + a0[2] + a0[3];
    dst[16] = a1[0] + a1[1] + a1[2] + a1[3];
    dst[32] = a2[0] + a2[1] + a2[2] + a2[3];
    dst[48] = a3[0] + a3[1] + a3[2] + a3[3];
  } else {
    int idx = bx - 80;
    int m = (idx & 3) * 256 + t;
    int n0 = (idx >> 2) * 64;
    float acc = 0.f;
    for (int n = n0; n < n0 + 64; ++n) acc = fmaf(Wa[n], W3[(size_t)n * DMID + m], acc);
    partial[(size_t)(idx >> 2) * DMID + m] = acc;
  }
}

// ---------------------------------------------------------------- FUSED producer/consumer:
// block (px, mg): 16 p-rows x 256 m (4 chunks of 64). Waves 0-3: MFMA pipeline,
// X chunk -> LDS (bf16). Waves 4-7: sigmoid of previous chunk between shared barriers.
#define GLDS(g, l) \
  __builtin_amdgcn_global_load_lds((const __attribute__((address_space(1))) void*)(g), \
                                   (__attribute__((address_space(3))) void*)(l), 16, 0, 0)

__global__ __launch_bounds__(512) void k_fused(const unsigned short* __restrict__ A,
                                               const unsigned short* __restrict__ Bw,
                                               const float* __restrict__ fwd,
                                               const float* __restrict__ partial,
                                               float* __restrict__ coefp) {
  __shared__ __align__(16) char smem[77568];
  unsigned short* As = (unsigned short*)smem;            // [3][1024] ushort (6 KB)
  unsigned short* Bs = (unsigned short*)(smem + 6144);   // [3][4096] ushort (24 KB)
  unsigned short* X0 = (unsigned short*)(smem + 30720);  // [16][66] bf16
  unsigned short* X1 = (unsigned short*)(smem + 32832);  // [16][66] bf16
  unsigned short* bl = (unsigned short*)(smem + 34944);  // [80][260] bf16 (41.6 KB)
  float*          wl = (float*)(smem + 76544);           // [256]

  int p0 = blockIdx.x * 16, mg = blockIdx.y;
  int t = threadIdx.x;
  int wid = t >> 6, l = t & 63;

  // producer state
  int aq = t & 127;                    // A chunk (waves 2,3 duplicate 0,1)
  int ar = aq >> 3, ac = aq & 7;
  const unsigned short* gA = A + (size_t)(p0 + ar) * 2048 + ((ac ^ (ar & 7)) << 3);
  int br = t >> 3, bc = t & 7;         // t in [0,256) for producers
  const unsigned short* gB0 = Bw + (size_t)(mg * 256 + br) * 2048 + ((bc ^ (br & 7)) << 3);
  const unsigned short* gB1 = Bw + (size_t)(mg * 256 + br + 32) * 2048 + ((bc ^ ((br + 32) & 7)) << 3);
  int ra = l & 15;
  int rb = wid * 16 + (l & 15);        // valid for producer wids 0-3
  int cc = l >> 4;
  int a_k0 = ra * 64 + (((cc) ^ (ra & 7)) << 3);
  int a_k1 = ra * 64 + (((cc + 4) ^ (ra & 7)) << 3);
  int b_k0 = rb * 64 + (((cc) ^ (rb & 7)) << 3);
  int b_k1 = rb * 64 + (((cc + 4) ^ (rb & 7)) << 3);

#define STAGE(bi, tile) do { \
    int ch_ = (tile) >> 5, kk_ = ((tile) & 31) * 64; \
    GLDS(gA + kk_, As + (bi) * 1024 + (t & 127) * 8); \
    GLDS(gB0 + (size_t)ch_ * 64 * 2048 + kk_, Bs + (bi) * 4096 + t * 8); \
    GLDS(gB1 + (size_t)ch_ * 64 * 2048 + kk_, Bs + (bi) * 4096 + t * 8 + 2048); \
  } while (0)
#define COMPUTE(bi) do { \
    const unsigned short* ap = As + (bi) * 1024; \
    const unsigned short* bp = Bs + (bi) * 4096; \
    bf16x8 A0 = *(const bf16x8*)(ap + a_k0); \
    bf16x8 B0 = *(const bf16x8*)(bp + b_k0); \
    acc = __builtin_amdgcn_mfma_f32_16x16x32_bf16(A0, B0, acc, 0, 0, 0); \
    bf16x8 A2 = *(const bf16x8*)(ap + a_k1); \
    bf16x8 B1 = *(const bf16x8*)(bp + b_k1); \
    acc = __builtin_amdgcn_mfma_f32_16x16x32_bf16(A2, B1, acc, 0, 0, 0); \
  } while (0)
#define XW(c) do { \
    unsigned short* Xp_ = ((c) & 1) ? X1 : X0; \
    int xr_ = (l >> 4) << 2, xc_ = wid * 16 + (l & 15); \
    _Pragma("unroll") \
    for (int q_ = 0; q_ < 4; ++q_) Xp_[(xr_ + q_) * 66 + xc_] = f2bf(acc[q_]); \
  } while (0)

  f32x4 acc = {0.f, 0.f, 0.f, 0.f};
  float sacc[5] = {0.f, 0.f, 0.f, 0.f, 0.f};
  int tc = t - 256;                    // consumer lane id
  int pi = tc >> 4, ci = tc & 15;      // (garbage for producers, unused)

  if (wid < 4) { STAGE(0, 0); STAGE(1, 1); }
  __syncthreads();                      // drains prologue (tiles 0,1 land)

  for (int s = 0; s <= 128; ++s) {
    if (wid < 4) {
      if (s < 128) {
        if (s && !(s & 31)) { XW((s >> 5) - 1); acc[0]=0.f; acc[1]=0.f; acc[2]=0.f; acc[3]=0.f; }
        if (s < 126) STAGE((s + 2) % 3, s + 2);
        COMPUTE(s % 3);
        if (s < 126) { asm volatile("s_waitcnt vmcnt(3)" ::: "memory"); }
        else         { asm volatile("s_waitcnt vmcnt(0)" ::: "memory"); }
        if (!(s & 31)) { asm volatile("s_waitcnt lgkmcnt(0)" ::: "memory"); }
      } else {
        XW(3);
        asm volatile("s_waitcnt lgkmcnt(0)" ::: "memory");
      }
    } else {
      if (s < 20) {                    // stage bl: 5120 ushort4-groups over 20 steps
        int g = s * 256 + tc;
        int row = g >> 6, mq = (g & 63) << 2;
        f32x4 v = *(const f32x4*)(fwd + (size_t)row * DMID + mg * 256 + mq);
        ushort4 h;
        h.x = f2bf(v[0]); h.y = f2bf(v[1]); h.z = f2bf(v[2]); h.w = f2bf(v[3]);
        *(ushort4*)&bl[row * 260 + mq] = h;
      } else if (s == 20) {            // stage wl
        float v = 0.f;
#pragma unroll
        for (int s16 = 0; s16 < 16; ++s16) v += partial[(size_t)s16 * DMID + mg * 256 + tc];
        wl[tc] = -2.f * v;
      }
      if (s == 32) { asm volatile("s_waitcnt lgkmcnt(0)" ::: "memory"); }
      int gs = s - 33;
      if (gs >= 0 && gs < 96) {        // sigmoid slice: chunk gs>>5, m-pair gs&31
        int ch = gs >> 5, k = gs & 31;
        const unsigned short* Xp = (ch & 1) ? X1 : X0;
        int moff = ch << 6;
        unsigned xa = *(const unsigned*)&Xp[pi * 66 + 2 * k];
        float a0 = bflo(xa), a1 = bfhi(xa);
        float wg0 = wl[moff + 2 * k], wg1 = wl[moff + 2 * k + 1];
#pragma unroll
        for (int kc = 0; kc < 5; ++kc) {
          unsigned bb = *(const unsigned*)&bl[(kc * 16 + ci) * 260 + moff + 2 * k];
          float b0 = bflo(bb), b1 = bfhi(bb);
          float e0 = __builtin_amdgcn_exp2f(a0 * b0);
          float e1 = __builtin_amdgcn_exp2f(a1 * b1);
          sacc[kc] = fmaf(wg0, __builtin_amdgcn_rcpf(1.f + e0), sacc[kc]);
          sacc[kc] = fmaf(wg1, __builtin_amdgcn_rcpf(1.f + e1), sacc[kc]);
        }
      }
    }
    __builtin_amdgcn_s_barrier();
    __builtin_amdgcn_sched_barrier(0);
  }

  if (wid >= 4) {                      // tail: chunk 3 (X1), barrier-free
#pragma unroll 1
    for (int k = 0; k < 32; ++k) {
      unsigned xa = *(const unsigned*)&X1[pi * 66 + 2 * k];
      float a0 = bflo(xa), a1 = bfhi(xa);
      float wg0 = wl[192 + 2 * k], wg1 = wl[192 + 2 * k + 1];
#pragma unroll
      for (int kc = 0; kc < 5; ++kc) {
        unsigned bb = *(const unsigned*)&bl[(kc * 16 + ci) * 260 + 192 + 2 * k];
        float b0 = bflo(bb), b1 = bfhi(bb);
        float e0 = __builtin_amdgcn_exp2f(a0 * b0);
        float e1 = __builtin_amdgcn_exp2f(a1 * b1);
        sacc[kc] = fmaf(wg0, __builtin_amdgcn_rcpf(1.f + e0), sacc[kc]);
        sacc[kc] = fmaf(wg1, __builtin_amdgcn_rcpf(1.f + e1), sacc[kc]);
      }
    }
    float* cp = coefp + (size_t)mg * (PN * NC);
#pragma unroll
    for (int kc = 0; kc < 5; ++kc)
      cp[(size_t)(p0 + pi) * NC + kc * 16 + ci] = sacc[kc];
  }
#undef STAGE
#undef COMPUTE
#undef XW
}

// ---------------------------------------------------------------- softmax + pooling; sums 4 coef partials
__global__ __launch_bounds__(256) void k_pool(const float* __restrict__ coefp,
                                              const float* __restrict__ img,
                                              float* __restrict__ out) {
  __shared__ __align__(16) float wt[HWN][16];
  __shared__ float red[16][16];
  __shared__ float mxs[16], inv[16];
  int dc = blockIdx.x * 256, cg = blockIdx.y * 16, b = blockIdx.z;
  int t = threadIdx.x;
  for (int i = t; i < HWN * 4; i += 256) {
    int hw = i >> 2, j4 = (i & 3) << 2;
    size_t o = (size_t)(b * HWN + hw) * NC + cg + j4;
    f32x4 s = {0.f, 0.f, 0.f, 0.f};
#pragma unroll
    for (int z = 0; z < PART; ++z) s += *(const f32x4*)&coefp[o + (size_t)z * (PN * NC)];
    *(f32x4*)&wt[hw][j4] = s;
  }
  __syncthreads();
  int j = t & 15, g = t >> 4;
  float pm = -1e30f;
  for (int hw = g; hw < HWN; hw += 16) pm = fmaxf(pm, wt[hw][j]);
  red[g][j] = pm;
  __syncthreads();
  if (t < 16) {
    float m = red[0][t];
#pragma unroll
    for (int g2 = 1; g2 < 16; ++g2) m = fmaxf(m, red[g2][t]);
    mxs[t] = m;
  }
  __syncthreads();
  float mj = mxs[j], ps = 0.f;
  for (int hw = g; hw < HWN; hw += 16) {
    float e = __builtin_amdgcn_exp2f((wt[hw][j] - mj) * 1.4426950408889634f);
    wt[hw][j] = e;
    ps += e;
  }
  red[g][j] = ps;
  __syncthreads();
  if (t < 16) {
    float s = 0.f;
#pragma unroll
    for (int g2 = 0; g2 < 16; ++g2) s += red[g2][t];
    inv[t] = 1.f / s;
  }
  __syncthreads();
  float acc[16];
#pragma unroll
  for (int q = 0; q < 16; ++q) acc[q] = 0.f;
  const float* fpd = img + ((size_t)b * DIMG + dc + t) * HWN;
  for (int hw = 0; hw < HWN; ++hw) {
    float v = fpd[hw];
#pragma unroll
    for (int q = 0; q < 16; ++q) acc[q] = fmaf(wt[hw][q], v, acc[q]);
  }
#pragma unroll
  for (int q = 0; q < 16; ++q)
    out[((size_t)b * NC + cg + q) * DIMG + dc + t] = acc[q] * inv[q];
}

// ----------------------------------------------------------------
extern "C" void kernel_launch(void* const* d_in, const int* in_sizes, int n_in,
                              void* d_out, int out_size, void* d_ws, size_t ws_size,
                              hipStream_t stream) {
  const float* img  = (const float*)d_in[1];
  const float* word = (const float*)d_in[2];
  const float* W1   = (const float*)d_in[3];
  const float* W2   = (const float*)d_in[4];
  const float* W3   = (const float*)d_in[5];
  const float* Wa   = (const float*)d_in[7];
  // b3 (d_in[6]) and ba (d_in[8]) are softmax-shift-invariant -> dropped.
  float* out = (float*)d_out;
  char* ws = (char*)d_ws;

  unsigned short* fmapH   = (unsigned short*)(ws + 0);         // 1600*2048*2 = 6,553,600
  unsigned short* W1h     = (unsigned short*)(ws + 6553600);   // 1024*2048*2 = 4,194,304
  float*          fwd     = (float*)(ws + 10747904);           //  96*1024*4 =   393,216
  float*          partial = (float*)(ws + 11141120);           //  16*1024*4 =    65,536
  float*          coefp   = (float*)(ws + 11206656);           // 4*1568*80*4 = 2,007,040

  hipLaunchKernelGGL(k_tc, dim3(5632), dim3(32, 8), 0, stream, img, fmapH, W1, W1h);
  hipLaunchKernelGGL(k_fwdweff, dim3(144), dim3(256), 0, stream,
                     word, W2, fwd, Wa, W3, partial);
  hipLaunchKernelGGL(k_fused, dim3(98, 4), dim3(512), 0, stream,
                     fmapH, W1h, fwd, partial, coefp);
  hipLaunchKernelGGL(k_pool, dim3(8, 5, 8), dim3(256), 0, stream, coefp, img, out);
  (void)in_sizes; (void)n_in; (void)out_size; (void)ws_size;
}

// Round 13
// 133.515 us; speedup vs baseline: 1.0487x; 1.0487x over previous
//
#include <hip/hip_runtime.h>
#include <hip/hip_bf16.h>
#include <stdint.h>

#define NB 8
#define DIMG 2048
#define HWN 196
#define PN 1568
#define DMID 1024
#define NC 80
#define DWORD 300
#define PART 8

typedef short bf16x8 __attribute__((ext_vector_type(8)));
typedef float f32x4 __attribute__((ext_vector_type(4)));

__device__ __forceinline__ unsigned short f2bf(float x) {
  union { float f; unsigned u; } c; c.f = x;
  unsigned r = c.u + 0x7FFFu + ((c.u >> 16) & 1u);
  return (unsigned short)(r >> 16);
}

// ---------------------------------------------------------------- transpose (bf16 only) + W1 cvt
__global__ void k_tc(const float* __restrict__ img, unsigned short* __restrict__ fmapH,
                     const float* __restrict__ W1, unsigned short* __restrict__ W1h) {
  __shared__ float tile[32][33];
  int bx = blockIdx.x;
  int tx = threadIdx.x, ty = threadIdx.y;
  if (bx < 3584) {
    int d0 = (bx & 63) * 32;
    int rem = bx >> 6;
    int h0 = (rem % 7) * 32, b = rem / 7;
    const float* src = img + (size_t)b * DIMG * HWN;
#pragma unroll
    for (int i = 0; i < 32; i += 8) {
      int hw = h0 + tx;
      tile[ty + i][tx] = (hw < HWN) ? src[(size_t)(d0 + ty + i) * HWN + hw] : 0.f;
    }
    __syncthreads();
#pragma unroll
    for (int i = 0; i < 32; i += 8) {
      int hw = h0 + ty + i;
      if (hw < HWN)
        fmapH[(size_t)(b * HWN + hw) * DIMG + d0 + tx] = f2bf(tile[tx][ty + i]);
    }
  } else {
    int tid = ty * 32 + tx;
    int i = ((bx - 3584) * 256 + tid) * 4;
    f32x4 v = *(const f32x4*)(W1 + i);
    ushort4 s;
    s.x = f2bf(v[0]); s.y = f2bf(v[1]); s.z = f2bf(v[2]); s.w = f2bf(v[3]);
    *(ushort4*)(W1h + i) = s;
  }
}

// ---------------------------------------------------------------- fwd + weff (coalesced, LDS-staged)
// fwd[c][m] = SC * sum_k word[c][k]*W2[m][k]  (SC = 2*log2e)
__global__ __launch_bounds__(256) void k_fwdweff(const float* __restrict__ word,
                                                 const float* __restrict__ W2,
                                                 float* __restrict__ fwd,
                                                 const float* __restrict__ Wa,
                                                 const float* __restrict__ W3,
                                                 float* __restrict__ partial) {
  __shared__ __align__(16) float w2s[64 * DWORD];   // 76.8 KB
  __shared__ __align__(16) float wds[16 * DWORD];   // 19.2 KB
  int bx = blockIdx.x, t = threadIdx.x;
  if (bx < 80) {
    int m0 = (bx & 15) * 64, c0 = (bx >> 4) * 16;
    const float SC = 2.8853900817779268f;  // 2*log2(e)
    for (int u = t; u < 64 * 75; u += 256) {
      int r = u / 75, q = u - r * 75;
      *(f32x4*)&w2s[r * DWORD + q * 4] =
          *(const f32x4*)(W2 + (size_t)(m0 + r) * DWORD + q * 4);
    }
    for (int u = t; u < 16 * 75; u += 256) {
      int r = u / 75, q = u - r * 75;
      f32x4 v = *(const f32x4*)(word + (size_t)(c0 + r) * DWORD + q * 4);
      *(f32x4*)&wds[r * DWORD + q * 4] = v * SC;
    }
    __syncthreads();
    int ci = t >> 4, mi = t & 15;
    f32x4 a0 = {0.f, 0.f, 0.f, 0.f}, a1 = a0, a2 = a0, a3 = a0;
    const float* wr = &wds[ci * DWORD];
    for (int q = 0; q < 75; ++q) {
      f32x4 wv = *(const f32x4*)&wr[q * 4];
      f32x4 b0 = *(const f32x4*)&w2s[(mi)*DWORD + q * 4];
      f32x4 b1 = *(const f32x4*)&w2s[(mi + 16) * DWORD + q * 4];
      f32x4 b2 = *(const f32x4*)&w2s[(mi + 32) * DWORD + q * 4];
      f32x4 b3 = *(const f32x4*)&w2s[(mi + 48) * DWORD + q * 4];
#pragma unroll
      for (int u = 0; u < 4; ++u) {
        a0[u] = fmaf(wv[u], b0[u], a0[u]);
        a1[u] = fmaf(wv[u], b1[u], a1[u]);
        a2[u] = fmaf(wv[u], b2[u], a2[u]);
        a3[u] = fmaf(wv[u], b3[u], a3[u]);
      }
    }
    float* dst = fwd + (size_t)(c0 + ci) * DMID + m0 + mi;
    dst[0]  = a0[0] + a0[1] + a0[2] + a0[3];
    dst[16] = a1[0] + a1[1] + a1[2] + a1[3];
    dst[32] = a2[0] + a2[1] + a2[2] + a2[3];
    dst[48] = a3[0] + a3[1] + a3[2] + a3[3];
  } else {
    int idx = bx - 80;
    int m = (idx & 3) * 256 + t;
    int n0 = (idx >> 2) * 64;
    float acc = 0.f;
    for (int n = n0; n < n0 + 64; ++n) acc = fmaf(Wa[n], W3[(size_t)n * DMID + m], acc);
    partial[(size_t)(idx >> 2) * DMID + m] = acc;
  }
}

// ---------------------------------------------------------------- GEMM (m97-structure, 128x128 tile, BK=32):
// fwh[1600][1024] = fmapH[1664][2048] x W1h[1024][2048]^T
#define GLDS(g, l) \
  __builtin_amdgcn_global_load_lds((const __attribute__((address_space(1))) void*)(g), \
                                   (__attribute__((address_space(3))) void*)(l), 16, 0, 0)

__global__ __launch_bounds__(256) void k_gemm(const unsigned short* __restrict__ A,
                                              const unsigned short* __restrict__ Bw,
                                              float* __restrict__ C) {
  __shared__ __align__(16) unsigned short As[128 * 32];  // 8 KB
  __shared__ __align__(16) unsigned short Bs[128 * 32];  // 8 KB
  int m0 = blockIdx.x * 128, n0 = blockIdx.y * 128;
  int t = threadIdx.x;
  int w = t >> 6, l = t & 63;
  int wr = w >> 1, wc = w & 1;          // 2x2 wave grid, 64x64 per wave
  f32x4 zero = {0.f, 0.f, 0.f, 0.f};
  f32x4 acc[4][4];
#pragma unroll
  for (int i = 0; i < 4; ++i)
#pragma unroll
    for (int j = 0; j < 4; ++j) acc[i][j] = zero;

  // staging: 512 chunks of 16B per matrix; thread t -> chunks t, t+256
  int sr = t >> 2, sk = (t & 3) << 3;
  const unsigned short* ga0 = A + (size_t)(m0 + sr) * 2048 + sk;
  const unsigned short* ga1 = A + (size_t)(m0 + 64 + sr) * 2048 + sk;
  const unsigned short* gb0 = Bw + (size_t)(n0 + sr) * 2048 + sk;
  const unsigned short* gb1 = Bw + (size_t)(n0 + 64 + sr) * 2048 + sk;

  int fr = l & 15, ko = (l >> 4) << 3;  // frag row-in-16, k-offset

  for (int kk = 0; kk < 2048; kk += 32) {
    __syncthreads();
    GLDS(ga0 + kk, As + t * 8);
    GLDS(ga1 + kk, As + t * 8 + 2048);
    GLDS(gb0 + kk, Bs + t * 8);
    GLDS(gb1 + kk, Bs + t * 8 + 2048);
    __syncthreads();
    bf16x8 a[4], b[4];
#pragma unroll
    for (int i = 0; i < 4; ++i)
      a[i] = *(const bf16x8*)&As[(wr * 64 + i * 16 + fr) * 32 + ko];
#pragma unroll
    for (int j = 0; j < 4; ++j)
      b[j] = *(const bf16x8*)&Bs[(wc * 64 + j * 16 + fr) * 32 + ko];
#pragma unroll
    for (int i = 0; i < 4; ++i)
#pragma unroll
      for (int j = 0; j < 4; ++j)
        acc[i][j] = __builtin_amdgcn_mfma_f32_16x16x32_bf16(a[i], b[j], acc[i][j], 0, 0, 0);
  }
  int cr = (l >> 4) << 2, cc = l & 15;
#pragma unroll
  for (int i = 0; i < 4; ++i) {
#pragma unroll
    for (int q = 0; q < 4; ++q) {
      int row = m0 + wr * 64 + i * 16 + cr + q;
      if (row < 1600) {
#pragma unroll
        for (int j = 0; j < 4; ++j)
          C[(size_t)row * DMID + n0 + wc * 64 + j * 16 + cc] = acc[i][j][q];
      }
    }
  }
}

// ---------------------------------------------------------------- coef logits, sigmoid-form, MC=128, mz=8
// tile: 64p x 16c x 128m; thread (pi,ci): p = p0+pi+16j (j<4), c = c0+ci
#define MC 128
__global__ __launch_bounds__(256) void k_coef(const float* __restrict__ fwh,
                                              const float* __restrict__ fwd,
                                              const float* __restrict__ partial,
                                              float* __restrict__ coefp) {
  __shared__ __align__(16) float al[64][132];   // 33.8 KB
  __shared__ __align__(16) float bl[16][132];   //  8.4 KB
  __shared__ __align__(16) float wl[MC];
  int p0 = blockIdx.x * 64, c0 = blockIdx.y * 16, mz = blockIdx.z;
  int mbase = mz * MC;
  int t = threadIdx.x;
  // ---- stage
  {
    int sra = t >> 2, sca = (t & 3) << 5;   // al: 8 x f32x4 per thread
    const float* gA = fwh + (size_t)(p0 + sra) * DMID + mbase + sca;
#pragma unroll
    for (int q = 0; q < 8; ++q)
      *(f32x4*)&al[sra][sca + q * 4] = *(const f32x4*)&gA[q * 4];
    int srb = t >> 4, scb = (t & 15) << 3;  // bl: 2 x f32x4 per thread
    const float* gB = fwd + (size_t)(c0 + srb) * DMID + mbase + scb;
#pragma unroll
    for (int q = 0; q < 2; ++q)
      *(f32x4*)&bl[srb][scb + q * 4] = *(const f32x4*)&gB[q * 4];
    if (t < MC) {                           // wl[m] = -2 * sum_s partial[s][m]
      float v = 0.f;
#pragma unroll
      for (int s = 0; s < 16; ++s) v += partial[(size_t)s * DMID + mbase + t];
      wl[t] = -2.f * v;
    }
  }
  __syncthreads();
  int pi = t >> 4, ci = t & 15;
  float acc[4];
#pragma unroll
  for (int j = 0; j < 4; ++j) acc[j] = 0.f;

  for (int mm = 0; mm < MC; mm += 4) {
    f32x4 wv = *(const f32x4*)&wl[mm];
    f32x4 bv = *(const f32x4*)&bl[ci][mm];
    f32x4 av0 = *(const f32x4*)&al[pi][mm];
    f32x4 av1 = *(const f32x4*)&al[pi + 16][mm];
    f32x4 av2 = *(const f32x4*)&al[pi + 32][mm];
    f32x4 av3 = *(const f32x4*)&al[pi + 48][mm];
#pragma unroll
    for (int u = 0; u < 4; ++u) {
      float w = wv[u], b = bv[u];
      float e0 = __builtin_amdgcn_exp2f(av0[u] * b);
      float e1 = __builtin_amdgcn_exp2f(av1[u] * b);
      float e2 = __builtin_amdgcn_exp2f(av2[u] * b);
      float e3 = __builtin_amdgcn_exp2f(av3[u] * b);
      acc[0] = fmaf(w, __builtin_amdgcn_rcpf(1.f + e0), acc[0]);
      acc[1] = fmaf(w, __builtin_amdgcn_rcpf(1.f + e1), acc[1]);
      acc[2] = fmaf(w, __builtin_amdgcn_rcpf(1.f + e2), acc[2]);
      acc[3] = fmaf(w, __builtin_amdgcn_rcpf(1.f + e3), acc[3]);
    }
  }
  float* cp = coefp + (size_t)mz * (PN * NC);
#pragma unroll
  for (int j = 0; j < 4; ++j) {
    int p = p0 + pi + 16 * j;
    if (p < PN) cp[(size_t)p * NC + c0 + ci] = acc[j];
  }
}

// ---------------------------------------------------------------- softmax + pooling; sums 8 coef partials
__global__ __launch_bounds__(256) void k_pool(const float* __restrict__ coefp,
                                              const float* __restrict__ img,
                                              float* __restrict__ out) {
  __shared__ __align__(16) float wt[HWN][16];
  __shared__ float red[16][16];
  __shared__ float mxs[16], inv[16];
  int dc = blockIdx.x * 256, cg = blockIdx.y * 16, b = blockIdx.z;
  int t = threadIdx.x;
  for (int i = t; i < HWN * 4; i += 256) {
    int hw = i >> 2, j4 = (i & 3) << 2;
    size_t o = (size_t)(b * HWN + hw) * NC + cg + j4;
    f32x4 s = {0.f, 0.f, 0.f, 0.f};
#pragma unroll
    for (int z = 0; z < PART; ++z) s += *(const f32x4*)&coefp[o + (size_t)z * (PN * NC)];
    *(f32x4*)&wt[hw][j4] = s;
  }
  __syncthreads();
  int j = t & 15, g = t >> 4;
  float pm = -1e30f;
  for (int hw = g; hw < HWN; hw += 16) pm = fmaxf(pm, wt[hw][j]);
  red[g][j] = pm;
  __syncthreads();
  if (t < 16) {
    float m = red[0][t];
#pragma unroll
    for (int g2 = 1; g2 < 16; ++g2) m = fmaxf(m, red[g2][t]);
    mxs[t] = m;
  }
  __syncthreads();
  float mj = mxs[j], ps = 0.f;
  for (int hw = g; hw < HWN; hw += 16) {
    float e = __builtin_amdgcn_exp2f((wt[hw][j] - mj) * 1.4426950408889634f);
    wt[hw][j] = e;
    ps += e;
  }
  red[g][j] = ps;
  __syncthreads();
  if (t < 16) {
    float s = 0.f;
#pragma unroll
    for (int g2 = 0; g2 < 16; ++g2) s += red[g2][t];
    inv[t] = 1.f / s;
  }
  __syncthreads();
  float acc[16];
#pragma unroll
  for (int q = 0; q < 16; ++q) acc[q] = 0.f;
  const float* fpd = img + ((size_t)b * DIMG + dc + t) * HWN;
  for (int hw = 0; hw < HWN; ++hw) {
    float v = fpd[hw];
#pragma unroll
    for (int q = 0; q < 16; ++q) acc[q] = fmaf(wt[hw][q], v, acc[q]);
  }
#pragma unroll
  for (int q = 0; q < 16; ++q)
    out[((size_t)b * NC + cg + q) * DIMG + dc + t] = acc[q] * inv[q];
}

// ----------------------------------------------------------------
extern "C" void kernel_launch(void* const* d_in, const int* in_sizes, int n_in,
                              void* d_out, int out_size, void* d_ws, size_t ws_size,
                              hipStream_t stream) {
  const float* img  = (const float*)d_in[1];
  const float* word = (const float*)d_in[2];
  const float* W1   = (const float*)d_in[3];
  const float* W2   = (const float*)d_in[4];
  const float* W3   = (const float*)d_in[5];
  const float* Wa   = (const float*)d_in[7];
  // b3 (d_in[6]) and ba (d_in[8]) are softmax-shift-invariant -> dropped.
  float* out = (float*)d_out;
  char* ws = (char*)d_ws;

  unsigned short* fmapH   = (unsigned short*)(ws + 0);         // 1664*2048*2 = 6,815,744 (rows 1568+ stale, finite)
  unsigned short* W1h     = (unsigned short*)(ws + 6815744);   // 1024*2048*2 = 4,194,304
  float*          fwh     = (float*)(ws + 11010048);           // 1600*1024*4 = 6,553,600
  float*          fwd     = (float*)(ws + 17563648);           //  96*1024*4 =   393,216
  float*          partial = (float*)(ws + 17956864);           //  16*1024*4 =    65,536
  float*          coefp   = (float*)(ws + 18022400);           // 8*1568*80*4 = 4,014,080

  hipLaunchKernelGGL(k_tc, dim3(5632), dim3(32, 8), 0, stream, img, fmapH, W1, W1h);
  hipLaunchKernelGGL(k_fwdweff, dim3(144), dim3(256), 0, stream,
                     word, W2, fwd, Wa, W3, partial);
  hipLaunchKernelGGL(k_gemm, dim3(13, 8), dim3(256), 0, stream, fmapH, W1h, fwh);
  hipLaunchKernelGGL(k_coef, dim3(25, 5, 8), dim3(256), 0, stream, fwh, fwd, partial, coefp);
  hipLaunchKernelGGL(k_pool, dim3(8, 5, 8), dim3(256), 0, stream, coefp, img, out);
  (void)in_sizes; (void)n_in; (void)out_size; (void)ws_size;
}

// Round 14
// 114.149 us; speedup vs baseline: 1.2266x; 1.1697x over previous
//
#include <hip/hip_runtime.h>
#include <hip/hip_bf16.h>
#include <stdint.h>

#define NB 8
#define DIMG 2048
#define HWN 196
#define PN 1568
#define DMID 1024
#define NC 80
#define DWORD 300
#define PART 8

typedef short bf16x8 __attribute__((ext_vector_type(8)));
typedef float f32x4 __attribute__((ext_vector_type(4)));

__device__ __forceinline__ unsigned short f2bf(float x) {
  union { float f; unsigned u; } c; c.f = x;
  unsigned r = c.u + 0x7FFFu + ((c.u >> 16) & 1u);
  return (unsigned short)(r >> 16);
}

// ---------------------------------------------------------------- transpose (bf16 only) + W1 cvt
__global__ void k_tc(const float* __restrict__ img, unsigned short* __restrict__ fmapH,
                     const float* __restrict__ W1, unsigned short* __restrict__ W1h) {
  __shared__ float tile[32][33];
  int bx = blockIdx.x;
  int tx = threadIdx.x, ty = threadIdx.y;
  if (bx < 3584) {
    int d0 = (bx & 63) * 32;
    int rem = bx >> 6;
    int h0 = (rem % 7) * 32, b = rem / 7;
    const float* src = img + (size_t)b * DIMG * HWN;
#pragma unroll
    for (int i = 0; i < 32; i += 8) {
      int hw = h0 + tx;
      tile[ty + i][tx] = (hw < HWN) ? src[(size_t)(d0 + ty + i) * HWN + hw] : 0.f;
    }
    __syncthreads();
#pragma unroll
    for (int i = 0; i < 32; i += 8) {
      int hw = h0 + ty + i;
      if (hw < HWN)
        fmapH[(size_t)(b * HWN + hw) * DIMG + d0 + tx] = f2bf(tile[tx][ty + i]);
    }
  } else {
    int tid = ty * 32 + tx;
    int i = ((bx - 3584) * 256 + tid) * 4;
    f32x4 v = *(const f32x4*)(W1 + i);
    ushort4 s;
    s.x = f2bf(v[0]); s.y = f2bf(v[1]); s.z = f2bf(v[2]); s.w = f2bf(v[3]);
    *(ushort4*)(W1h + i) = s;
  }
}

// ---------------------------------------------------------------- fwd + weff (coalesced, LDS-staged)
// fwd[c][m] = SC * sum_k word[c][k]*W2[m][k]  (SC = 2*log2e)
__global__ __launch_bounds__(256) void k_fwdweff(const float* __restrict__ word,
                                                 const float* __restrict__ W2,
                                                 float* __restrict__ fwd,
                                                 const float* __restrict__ Wa,
                                                 const float* __restrict__ W3,
                                                 float* __restrict__ partial) {
  __shared__ __align__(16) float w2s[64 * DWORD];   // 76.8 KB
  __shared__ __align__(16) float wds[16 * DWORD];   // 19.2 KB
  int bx = blockIdx.x, t = threadIdx.x;
  if (bx < 80) {
    int m0 = (bx & 15) * 64, c0 = (bx >> 4) * 16;
    const float SC = 2.8853900817779268f;  // 2*log2(e)
    for (int u = t; u < 64 * 75; u += 256) {
      int r = u / 75, q = u - r * 75;
      *(f32x4*)&w2s[r * DWORD + q * 4] =
          *(const f32x4*)(W2 + (size_t)(m0 + r) * DWORD + q * 4);
    }
    for (int u = t; u < 16 * 75; u += 256) {
      int r = u / 75, q = u - r * 75;
      f32x4 v = *(const f32x4*)(word + (size_t)(c0 + r) * DWORD + q * 4);
      *(f32x4*)&wds[r * DWORD + q * 4] = v * SC;
    }
    __syncthreads();
    int ci = t >> 4, mi = t & 15;
    f32x4 a0 = {0.f, 0.f, 0.f, 0.f}, a1 = a0, a2 = a0, a3 = a0;
    const float* wr = &wds[ci * DWORD];
    for (int q = 0; q < 75; ++q) {
      f32x4 wv = *(const f32x4*)&wr[q * 4];
      f32x4 b0 = *(const f32x4*)&w2s[(mi)*DWORD + q * 4];
      f32x4 b1 = *(const f32x4*)&w2s[(mi + 16) * DWORD + q * 4];
      f32x4 b2 = *(const f32x4*)&w2s[(mi + 32) * DWORD + q * 4];
      f32x4 b3 = *(const f32x4*)&w2s[(mi + 48) * DWORD + q * 4];
#pragma unroll
      for (int u = 0; u < 4; ++u) {
        a0[u] = fmaf(wv[u], b0[u], a0[u]);
        a1[u] = fmaf(wv[u], b1[u], a1[u]);
        a2[u] = fmaf(wv[u], b2[u], a2[u]);
        a3[u] = fmaf(wv[u], b3[u], a3[u]);
      }
    }
    float* dst = fwd + (size_t)(c0 + ci) * DMID + m0 + mi;
    dst[0]  = a0[0] + a0[1] + a0[2] + a0[3];
    dst[16] = a1[0] + a1[1] + a1[2] + a1[3];
    dst[32] = a2[0] + a2[1] + a2[2] + a2[3];
    dst[48] = a3[0] + a3[1] + a3[2] + a3[3];
  } else {
    int idx = bx - 80;
    int m = (idx & 3) * 256 + t;
    int n0 = (idx >> 2) * 64;
    float acc = 0.f;
    for (int n = n0; n < n0 + 64; ++n) acc = fmaf(Wa[n], W3[(size_t)n * DMID + m], acc);
    partial[(size_t)(idx >> 2) * DMID + m] = acc;
  }
}

// ---------------------------------------------------------------- GEMM (proven R8 shape): 64x64 tile, BK=64,
// triple-buffered 2-deep prefetch, counted vmcnt(4), XOR chunk-swizzled LDS. Grid 25x16 = 400 blocks.
#define GLDS(g, l) \
  __builtin_amdgcn_global_load_lds((const __attribute__((address_space(1))) void*)(g), \
                                   (__attribute__((address_space(3))) void*)(l), 16, 0, 0)

__global__ __launch_bounds__(256) void k_gemm(const unsigned short* __restrict__ A,
                                              const unsigned short* __restrict__ Bw,
                                              float* __restrict__ C) {
  __shared__ __align__(16) unsigned short As[3][64 * 64];
  __shared__ __align__(16) unsigned short Bs[3][64 * 64];
  int m0 = blockIdx.x * 64, n0 = blockIdx.y * 64;
  int t = threadIdx.x;
  int w = t >> 6, l = t & 63;
  int wr = w >> 1, wc = w & 1;
  f32x4 zero = {0.f, 0.f, 0.f, 0.f};
  f32x4 acc00 = zero, acc01 = zero, acc10 = zero, acc11 = zero;

  int r0 = t >> 3, c0 = t & 7;
  int r1 = r0 + 32;
  const unsigned short* ga0 = A + (size_t)(m0 + r0) * 2048 + ((c0 ^ (r0 & 7)) << 3);
  const unsigned short* ga1 = A + (size_t)(m0 + r1) * 2048 + ((c0 ^ (r1 & 7)) << 3);
  const unsigned short* gb0 = Bw + (size_t)(n0 + r0) * 2048 + ((c0 ^ (r0 & 7)) << 3);
  const unsigned short* gb1 = Bw + (size_t)(n0 + r1) * 2048 + ((c0 ^ (r1 & 7)) << 3);

  int ra = wr * 32 + (l & 15);
  int rb = wc * 32 + (l & 15);
  int cc = l >> 4;
  int a_k0 = ra * 64 + (((cc) ^ (ra & 7)) << 3);
  int a_k1 = ra * 64 + (((cc + 4) ^ (ra & 7)) << 3);
  int b_k0 = rb * 64 + (((cc) ^ (rb & 7)) << 3);
  int b_k1 = rb * 64 + (((cc + 4) ^ (rb & 7)) << 3);

#define STAGE(bi, kk) do { \
    GLDS(ga0 + (kk), &As[bi][t * 8]); \
    GLDS(ga1 + (kk), &As[bi][t * 8 + 2048]); \
    GLDS(gb0 + (kk), &Bs[bi][t * 8]); \
    GLDS(gb1 + (kk), &Bs[bi][t * 8 + 2048]); \
  } while (0)

#define COMPUTE(bi) do { \
    const unsigned short* ap = As[bi]; \
    const unsigned short* bp = Bs[bi]; \
    bf16x8 A0 = *(const bf16x8*)(ap + a_k0); \
    bf16x8 A1 = *(const bf16x8*)(ap + a_k0 + 1024); \
    bf16x8 B0 = *(const bf16x8*)(bp + b_k0); \
    bf16x8 B1 = *(const bf16x8*)(bp + b_k0 + 1024); \
    acc00 = __builtin_amdgcn_mfma_f32_16x16x32_bf16(A0, B0, acc00, 0, 0, 0); \
    acc01 = __builtin_amdgcn_mfma_f32_16x16x32_bf16(A0, B1, acc01, 0, 0, 0); \
    acc10 = __builtin_amdgcn_mfma_f32_16x16x32_bf16(A1, B0, acc10, 0, 0, 0); \
    acc11 = __builtin_amdgcn_mfma_f32_16x16x32_bf16(A1, B1, acc11, 0, 0, 0); \
    bf16x8 A2 = *(const bf16x8*)(ap + a_k1); \
    bf16x8 A3 = *(const bf16x8*)(ap + a_k1 + 1024); \
    bf16x8 B2 = *(const bf16x8*)(bp + b_k1); \
    bf16x8 B3 = *(const bf16x8*)(bp + b_k1 + 1024); \
    acc00 = __builtin_amdgcn_mfma_f32_16x16x32_bf16(A2, B2, acc00, 0, 0, 0); \
    acc01 = __builtin_amdgcn_mfma_f32_16x16x32_bf16(A2, B3, acc01, 0, 0, 0); \
    acc10 = __builtin_amdgcn_mfma_f32_16x16x32_bf16(A3, B2, acc10, 0, 0, 0); \
    acc11 = __builtin_amdgcn_mfma_f32_16x16x32_bf16(A3, B3, acc11, 0, 0, 0); \
  } while (0)

  STAGE(0, 0);
  STAGE(1, 64);
  asm volatile("s_waitcnt vmcnt(4)" ::: "memory");
  __builtin_amdgcn_s_barrier();
  __builtin_amdgcn_sched_barrier(0);
  for (int kt = 0; kt < 32; ++kt) {
    int cur = kt % 3;
    if (kt < 30) STAGE((kt + 2) % 3, (kt + 2) * 64);
    COMPUTE(cur);
    if (kt < 30) {
      asm volatile("s_waitcnt vmcnt(4)" ::: "memory");
      __builtin_amdgcn_s_barrier();
      __builtin_amdgcn_sched_barrier(0);
    } else if (kt == 30) {
      asm volatile("s_waitcnt vmcnt(0)" ::: "memory");
      __builtin_amdgcn_s_barrier();
      __builtin_amdgcn_sched_barrier(0);
    }
  }
  int cr = (l >> 4) << 2, ccn = l & 15;
#pragma unroll
  for (int q = 0; q < 4; ++q) {
    C[(size_t)(m0 + wr * 32 + cr + q) * DMID + n0 + wc * 32 + ccn] = acc00[q];
    C[(size_t)(m0 + wr * 32 + cr + q) * DMID + n0 + wc * 32 + 16 + ccn] = acc01[q];
    C[(size_t)(m0 + wr * 32 + 16 + cr + q) * DMID + n0 + wc * 32 + ccn] = acc10[q];
    C[(size_t)(m0 + wr * 32 + 16 + cr + q) * DMID + n0 + wc * 32 + 16 + ccn] = acc11[q];
  }
#undef STAGE
#undef COMPUTE
}

// ---------------------------------------------------------------- coef logits, sigmoid-form, MC=128, mz=8
// tile: 64p x 16c x 128m; thread (pi,ci): p = p0+pi+16j (j<4), c = c0+ci
#define MC 128
__global__ __launch_bounds__(256) void k_coef(const float* __restrict__ fwh,
                                              const float* __restrict__ fwd,
                                              const float* __restrict__ partial,
                                              float* __restrict__ coefp) {
  __shared__ __align__(16) float al[64][132];   // 33.8 KB
  __shared__ __align__(16) float bl[16][132];   //  8.4 KB
  __shared__ __align__(16) float wl[MC];
  int p0 = blockIdx.x * 64, c0 = blockIdx.y * 16, mz = blockIdx.z;
  int mbase = mz * MC;
  int t = threadIdx.x;
  // ---- stage
  {
    int sra = t >> 2, sca = (t & 3) << 5;   // al: 8 x f32x4 per thread
    const float* gA = fwh + (size_t)(p0 + sra) * DMID + mbase + sca;
#pragma unroll
    for (int q = 0; q < 8; ++q)
      *(f32x4*)&al[sra][sca + q * 4] = *(const f32x4*)&gA[q * 4];
    int srb = t >> 4, scb = (t & 15) << 3;  // bl: 2 x f32x4 per thread
    const float* gB = fwd + (size_t)(c0 + srb) * DMID + mbase + scb;
#pragma unroll
    for (int q = 0; q < 2; ++q)
      *(f32x4*)&bl[srb][scb + q * 4] = *(const f32x4*)&gB[q * 4];
    if (t < MC) {                           // wl[m] = -2 * sum_s partial[s][m]
      float v = 0.f;
#pragma unroll
      for (int s = 0; s < 16; ++s) v += partial[(size_t)s * DMID + mbase + t];
      wl[t] = -2.f * v;
    }
  }
  __syncthreads();
  int pi = t >> 4, ci = t & 15;
  float acc[4];
#pragma unroll
  for (int j = 0; j < 4; ++j) acc[j] = 0.f;

  for (int mm = 0; mm < MC; mm += 4) {
    f32x4 wv = *(const f32x4*)&wl[mm];
    f32x4 bv = *(const f32x4*)&bl[ci][mm];
    f32x4 av0 = *(const f32x4*)&al[pi][mm];
    f32x4 av1 = *(const f32x4*)&al[pi + 16][mm];
    f32x4 av2 = *(const f32x4*)&al[pi + 32][mm];
    f32x4 av3 = *(const f32x4*)&al[pi + 48][mm];
#pragma unroll
    for (int u = 0; u < 4; ++u) {
      float w = wv[u], b = bv[u];
      float e0 = __builtin_amdgcn_exp2f(av0[u] * b);
      float e1 = __builtin_amdgcn_exp2f(av1[u] * b);
      float e2 = __builtin_amdgcn_exp2f(av2[u] * b);
      float e3 = __builtin_amdgcn_exp2f(av3[u] * b);
      acc[0] = fmaf(w, __builtin_amdgcn_rcpf(1.f + e0), acc[0]);
      acc[1] = fmaf(w, __builtin_amdgcn_rcpf(1.f + e1), acc[1]);
      acc[2] = fmaf(w, __builtin_amdgcn_rcpf(1.f + e2), acc[2]);
      acc[3] = fmaf(w, __builtin_amdgcn_rcpf(1.f + e3), acc[3]);
    }
  }
  float* cp = coefp + (size_t)mz * (PN * NC);
#pragma unroll
  for (int j = 0; j < 4; ++j) {
    int p = p0 + pi + 16 * j;
    if (p < PN) cp[(size_t)p * NC + c0 + ci] = acc[j];
  }
}

// ---------------------------------------------------------------- softmax + pooling; sums 8 coef partials
__global__ __launch_bounds__(256) void k_pool(const float* __restrict__ coefp,
                                              const float* __restrict__ img,
                                              float* __restrict__ out) {
  __shared__ __align__(16) float wt[HWN][16];
  __shared__ float red[16][16];
  __shared__ float mxs[16], inv[16];
  int dc = blockIdx.x * 256, cg = blockIdx.y * 16, b = blockIdx.z;
  int t = threadIdx.x;
  for (int i = t; i < HWN * 4; i += 256) {
    int hw = i >> 2, j4 = (i & 3) << 2;
    size_t o = (size_t)(b * HWN + hw) * NC + cg + j4;
    f32x4 s = {0.f, 0.f, 0.f, 0.f};
#pragma unroll
    for (int z = 0; z < PART; ++z) s += *(const f32x4*)&coefp[o + (size_t)z * (PN * NC)];
    *(f32x4*)&wt[hw][j4] = s;
  }
  __syncthreads();
  int j = t & 15, g = t >> 4;
  float pm = -1e30f;
  for (int hw = g; hw < HWN; hw += 16) pm = fmaxf(pm, wt[hw][j]);
  red[g][j] = pm;
  __syncthreads();
  if (t < 16) {
    float m = red[0][t];
#pragma unroll
    for (int g2 = 1; g2 < 16; ++g2) m = fmaxf(m, red[g2][t]);
    mxs[t] = m;
  }
  __syncthreads();
  float mj = mxs[j], ps = 0.f;
  for (int hw = g; hw < HWN; hw += 16) {
    float e = __builtin_amdgcn_exp2f((wt[hw][j] - mj) * 1.4426950408889634f);
    wt[hw][j] = e;
    ps += e;
  }
  red[g][j] = ps;
  __syncthreads();
  if (t < 16) {
    float s = 0.f;
#pragma unroll
    for (int g2 = 0; g2 < 16; ++g2) s += red[g2][t];
    inv[t] = 1.f / s;
  }
  __syncthreads();
  float acc[16];
#pragma unroll
  for (int q = 0; q < 16; ++q) acc[q] = 0.f;
  const float* fpd = img + ((size_t)b * DIMG + dc + t) * HWN;
  for (int hw = 0; hw < HWN; ++hw) {
    float v = fpd[hw];
#pragma unroll
    for (int q = 0; q < 16; ++q) acc[q] = fmaf(wt[hw][q], v, acc[q]);
  }
#pragma unroll
  for (int q = 0; q < 16; ++q)
    out[((size_t)b * NC + cg + q) * DIMG + dc + t] = acc[q] * inv[q];
}

// ----------------------------------------------------------------
extern "C" void kernel_launch(void* const* d_in, const int* in_sizes, int n_in,
                              void* d_out, int out_size, void* d_ws, size_t ws_size,
                              hipStream_t stream) {
  const float* img  = (const float*)d_in[1];
  const float* word = (const float*)d_in[2];
  const float* W1   = (const float*)d_in[3];
  const float* W2   = (const float*)d_in[4];
  const float* W3   = (const float*)d_in[5];
  const float* Wa   = (const float*)d_in[7];
  // b3 (d_in[6]) and ba (d_in[8]) are softmax-shift-invariant -> dropped.
  float* out = (float*)d_out;
  char* ws = (char*)d_ws;

  unsigned short* fmapH   = (unsigned short*)(ws + 0);         // 1600*2048*2 = 6,553,600
  unsigned short* W1h     = (unsigned short*)(ws + 6553600);   // 1024*2048*2 = 4,194,304
  float*          fwh     = (float*)(ws + 10747904);           // 1600*1024*4 = 6,553,600
  float*          fwd     = (float*)(ws + 17301504);           //  96*1024*4 =   393,216
  float*          partial = (float*)(ws + 17694720);           //  16*1024*4 =    65,536
  float*          coefp   = (float*)(ws + 17760256);           // 8*1568*80*4 = 4,014,080

  hipLaunchKernelGGL(k_tc, dim3(5632), dim3(32, 8), 0, stream, img, fmapH, W1, W1h);
  hipLaunchKernelGGL(k_fwdweff, dim3(144), dim3(256), 0, stream,
                     word, W2, fwd, Wa, W3, partial);
  hipLaunchKernelGGL(k_gemm, dim3(25, 16), dim3(256), 0, stream, fmapH, W1h, fwh);
  hipLaunchKernelGGL(k_coef, dim3(25, 5, 8), dim3(256), 0, stream, fwh, fwd, partial, coefp);
  hipLaunchKernelGGL(k_pool, dim3(8, 5, 8), dim3(256), 0, stream, coefp, img, out);
  (void)in_sizes; (void)n_in; (void)out_size; (void)ws_size;
}

// Round 15
// 113.299 us; speedup vs baseline: 1.2358x; 1.0075x over previous
//
#include <hip/hip_runtime.h>
#include <hip/hip_bf16.h>
#include <stdint.h>

#define NB 8
#define DIMG 2048
#define HWN 196
#define PN 1568
#define DMID 1024
#define NC 80
#define DWORD 300
#define PART 8

typedef short bf16x8 __attribute__((ext_vector_type(8)));
typedef float f32x4 __attribute__((ext_vector_type(4)));

__device__ __forceinline__ unsigned short f2bf(float x) {
  union { float f; unsigned u; } c; c.f = x;
  unsigned r = c.u + 0x7FFFu + ((c.u >> 16) & 1u);
  return (unsigned short)(r >> 16);
}

// ---------------------------------------------------------------- transpose (bf16 only) + W1 cvt
__global__ void k_tc(const float* __restrict__ img, unsigned short* __restrict__ fmapH,
                     const float* __restrict__ W1, unsigned short* __restrict__ W1h) {
  __shared__ float tile[32][33];
  int bx = blockIdx.x;
  int tx = threadIdx.x, ty = threadIdx.y;
  if (bx < 3584) {
    int d0 = (bx & 63) * 32;
    int rem = bx >> 6;
    int h0 = (rem % 7) * 32, b = rem / 7;
    const float* src = img + (size_t)b * DIMG * HWN;
#pragma unroll
    for (int i = 0; i < 32; i += 8) {
      int hw = h0 + tx;
      tile[ty + i][tx] = (hw < HWN) ? src[(size_t)(d0 + ty + i) * HWN + hw] : 0.f;
    }
    __syncthreads();
#pragma unroll
    for (int i = 0; i < 32; i += 8) {
      int hw = h0 + ty + i;
      if (hw < HWN)
        fmapH[(size_t)(b * HWN + hw) * DIMG + d0 + tx] = f2bf(tile[tx][ty + i]);
    }
  } else {
    int tid = ty * 32 + tx;
    int i = ((bx - 3584) * 256 + tid) * 4;
    f32x4 v = *(const f32x4*)(W1 + i);
    ushort4 s;
    s.x = f2bf(v[0]); s.y = f2bf(v[1]); s.z = f2bf(v[2]); s.w = f2bf(v[3]);
    *(ushort4*)(W1h + i) = s;
  }
}

// ---------------------------------------------------------------- fwd + weff (coalesced, LDS-staged)
// fwd[c][m] = SC * sum_k word[c][k]*W2[m][k]  (SC = 2*log2e)
__global__ __launch_bounds__(256) void k_fwdweff(const float* __restrict__ word,
                                                 const float* __restrict__ W2,
                                                 float* __restrict__ fwd,
                                                 const float* __restrict__ Wa,
                                                 const float* __restrict__ W3,
                                                 float* __restrict__ partial) {
  __shared__ __align__(16) float w2s[64 * DWORD];   // 76.8 KB
  __shared__ __align__(16) float wds[16 * DWORD];   // 19.2 KB
  int bx = blockIdx.x, t = threadIdx.x;
  if (bx < 80) {
    int m0 = (bx & 15) * 64, c0 = (bx >> 4) * 16;
    const float SC = 2.8853900817779268f;  // 2*log2(e)
    for (int u = t; u < 64 * 75; u += 256) {
      int r = u / 75, q = u - r * 75;
      *(f32x4*)&w2s[r * DWORD + q * 4] =
          *(const f32x4*)(W2 + (size_t)(m0 + r) * DWORD + q * 4);
    }
    for (int u = t; u < 16 * 75; u += 256) {
      int r = u / 75, q = u - r * 75;
      f32x4 v = *(const f32x4*)(word + (size_t)(c0 + r) * DWORD + q * 4);
      *(f32x4*)&wds[r * DWORD + q * 4] = v * SC;
    }
    __syncthreads();
    int ci = t >> 4, mi = t & 15;
    f32x4 a0 = {0.f, 0.f, 0.f, 0.f}, a1 = a0, a2 = a0, a3 = a0;
    const float* wr = &wds[ci * DWORD];
    for (int q = 0; q < 75; ++q) {
      f32x4 wv = *(const f32x4*)&wr[q * 4];
      f32x4 b0 = *(const f32x4*)&w2s[(mi)*DWORD + q * 4];
      f32x4 b1 = *(const f32x4*)&w2s[(mi + 16) * DWORD + q * 4];
      f32x4 b2 = *(const f32x4*)&w2s[(mi + 32) * DWORD + q * 4];
      f32x4 b3 = *(const f32x4*)&w2s[(mi + 48) * DWORD + q * 4];
#pragma unroll
      for (int u = 0; u < 4; ++u) {
        a0[u] = fmaf(wv[u], b0[u], a0[u]);
        a1[u] = fmaf(wv[u], b1[u], a1[u]);
        a2[u] = fmaf(wv[u], b2[u], a2[u]);
        a3[u] = fmaf(wv[u], b3[u], a3[u]);
      }
    }
    float* dst = fwd + (size_t)(c0 + ci) * DMID + m0 + mi;
    dst[0]  = a0[0] + a0[1] + a0[2] + a0[3];
    dst[16] = a1[0] + a1[1] + a1[2] + a1[3];
    dst[32] = a2[0] + a2[1] + a2[2] + a2[3];
    dst[48] = a3[0] + a3[1] + a3[2] + a3[3];
  } else {
    int idx = bx - 80;
    int m = (idx & 3) * 256 + t;
    int n0 = (idx >> 2) * 64;
    float acc = 0.f;
    for (int n = n0; n < n0 + 64; ++n) acc = fmaf(Wa[n], W3[(size_t)n * DMID + m], acc);
    partial[(size_t)(idx >> 2) * DMID + m] = acc;
  }
}

// ---------------------------------------------------------------- GEMM, K-split-2: grid (25,16,2), 800 blocks.
// fwhp[kz][1600][1024] = fmapH[.][kz*1024 : +1024] x W1h[.][kz*1024 : +1024]^T
#define GLDS(g, l) \
  __builtin_amdgcn_global_load_lds((const __attribute__((address_space(1))) void*)(g), \
                                   (__attribute__((address_space(3))) void*)(l), 16, 0, 0)

__global__ __launch_bounds__(256) void k_gemm(const unsigned short* __restrict__ A,
                                              const unsigned short* __restrict__ Bw,
                                              float* __restrict__ C) {
  __shared__ __align__(16) unsigned short As[3][64 * 64];
  __shared__ __align__(16) unsigned short Bs[3][64 * 64];
  int m0 = blockIdx.x * 64, n0 = blockIdx.y * 64;
  int koff = blockIdx.z * 1024;
  int t = threadIdx.x;
  int w = t >> 6, l = t & 63;
  int wr = w >> 1, wc = w & 1;
  f32x4 zero = {0.f, 0.f, 0.f, 0.f};
  f32x4 acc00 = zero, acc01 = zero, acc10 = zero, acc11 = zero;

  int r0 = t >> 3, c0 = t & 7;
  int r1 = r0 + 32;
  const unsigned short* ga0 = A + (size_t)(m0 + r0) * 2048 + koff + ((c0 ^ (r0 & 7)) << 3);
  const unsigned short* ga1 = A + (size_t)(m0 + r1) * 2048 + koff + ((c0 ^ (r1 & 7)) << 3);
  const unsigned short* gb0 = Bw + (size_t)(n0 + r0) * 2048 + koff + ((c0 ^ (r0 & 7)) << 3);
  const unsigned short* gb1 = Bw + (size_t)(n0 + r1) * 2048 + koff + ((c0 ^ (r1 & 7)) << 3);

  int ra = wr * 32 + (l & 15);
  int rb = wc * 32 + (l & 15);
  int cc = l >> 4;
  int a_k0 = ra * 64 + (((cc) ^ (ra & 7)) << 3);
  int a_k1 = ra * 64 + (((cc + 4) ^ (ra & 7)) << 3);
  int b_k0 = rb * 64 + (((cc) ^ (rb & 7)) << 3);
  int b_k1 = rb * 64 + (((cc + 4) ^ (rb & 7)) << 3);

#define STAGE(bi, kk) do { \
    GLDS(ga0 + (kk), &As[bi][t * 8]); \
    GLDS(ga1 + (kk), &As[bi][t * 8 + 2048]); \
    GLDS(gb0 + (kk), &Bs[bi][t * 8]); \
    GLDS(gb1 + (kk), &Bs[bi][t * 8 + 2048]); \
  } while (0)

#define COMPUTE(bi) do { \
    const unsigned short* ap = As[bi]; \
    const unsigned short* bp = Bs[bi]; \
    bf16x8 A0 = *(const bf16x8*)(ap + a_k0); \
    bf16x8 A1 = *(const bf16x8*)(ap + a_k0 + 1024); \
    bf16x8 B0 = *(const bf16x8*)(bp + b_k0); \
    bf16x8 B1 = *(const bf16x8*)(bp + b_k0 + 1024); \
    acc00 = __builtin_amdgcn_mfma_f32_16x16x32_bf16(A0, B0, acc00, 0, 0, 0); \
    acc01 = __builtin_amdgcn_mfma_f32_16x16x32_bf16(A0, B1, acc01, 0, 0, 0); \
    acc10 = __builtin_amdgcn_mfma_f32_16x16x32_bf16(A1, B0, acc10, 0, 0, 0); \
    acc11 = __builtin_amdgcn_mfma_f32_16x16x32_bf16(A1, B1, acc11, 0, 0, 0); \
    bf16x8 A2 = *(const bf16x8*)(ap + a_k1); \
    bf16x8 A3 = *(const bf16x8*)(ap + a_k1 + 1024); \
    bf16x8 B2 = *(const bf16x8*)(bp + b_k1); \
    bf16x8 B3 = *(const bf16x8*)(bp + b_k1 + 1024); \
    acc00 = __builtin_amdgcn_mfma_f32_16x16x32_bf16(A2, B2, acc00, 0, 0, 0); \
    acc01 = __builtin_amdgcn_mfma_f32_16x16x32_bf16(A2, B3, acc01, 0, 0, 0); \
    acc10 = __builtin_amdgcn_mfma_f32_16x16x32_bf16(A3, B2, acc10, 0, 0, 0); \
    acc11 = __builtin_amdgcn_mfma_f32_16x16x32_bf16(A3, B3, acc11, 0, 0, 0); \
  } while (0)

  STAGE(0, 0);
  STAGE(1, 64);
  asm volatile("s_waitcnt vmcnt(4)" ::: "memory");
  __builtin_amdgcn_s_barrier();
  __builtin_amdgcn_sched_barrier(0);
  for (int kt = 0; kt < 16; ++kt) {
    int cur = kt % 3;
    if (kt < 14) STAGE((kt + 2) % 3, (kt + 2) * 64);
    COMPUTE(cur);
    if (kt < 14) {
      asm volatile("s_waitcnt vmcnt(4)" ::: "memory");
      __builtin_amdgcn_s_barrier();
      __builtin_amdgcn_sched_barrier(0);
    } else if (kt == 14) {
      asm volatile("s_waitcnt vmcnt(0)" ::: "memory");
      __builtin_amdgcn_s_barrier();
      __builtin_amdgcn_sched_barrier(0);
    }
  }
  float* Cz = C + (size_t)blockIdx.z * (1600 * DMID);
  int cr = (l >> 4) << 2, ccn = l & 15;
#pragma unroll
  for (int q = 0; q < 4; ++q) {
    Cz[(size_t)(m0 + wr * 32 + cr + q) * DMID + n0 + wc * 32 + ccn] = acc00[q];
    Cz[(size_t)(m0 + wr * 32 + cr + q) * DMID + n0 + wc * 32 + 16 + ccn] = acc01[q];
    Cz[(size_t)(m0 + wr * 32 + 16 + cr + q) * DMID + n0 + wc * 32 + ccn] = acc10[q];
    Cz[(size_t)(m0 + wr * 32 + 16 + cr + q) * DMID + n0 + wc * 32 + 16 + ccn] = acc11[q];
  }
#undef STAGE
#undef COMPUTE
}

// ---------------------------------------------------------------- coef logits: sums 2 fwh K-halves on stage,
// MC=64 (LDS 22 KB, fully-resident grid), mz=8 (128 m per block)
#define MC 64
__global__ __launch_bounds__(256) void k_coef(const float* __restrict__ fwhp,
                                              const float* __restrict__ fwd,
                                              const float* __restrict__ partial,
                                              float* __restrict__ coefp) {
  __shared__ __align__(16) float al[64][68];   // 17.4 KB
  __shared__ __align__(16) float bl[16][68];   //  4.3 KB
  __shared__ __align__(16) float wl[MC];
  int p0 = blockIdx.x * 64, c0 = blockIdx.y * 16, mz = blockIdx.z;
  int t = threadIdx.x;
  int pi = t >> 4, ci = t & 15;
  float acc[4];
#pragma unroll
  for (int j = 0; j < 4; ++j) acc[j] = 0.f;

  const float* fwh0 = fwhp;
  const float* fwh1 = fwhp + (size_t)1600 * DMID;

  for (int mc = 0; mc < 2; ++mc) {
    int mbase = mz * 128 + mc * MC;
    __syncthreads();
    {
      int sra = t >> 2, sca = (t & 3) << 4;   // al: 4 x f32x4 per thread
      const float* gA0 = fwh0 + (size_t)(p0 + sra) * DMID + mbase + sca;
      const float* gA1 = fwh1 + (size_t)(p0 + sra) * DMID + mbase + sca;
#pragma unroll
      for (int q = 0; q < 4; ++q) {
        f32x4 v = *(const f32x4*)&gA0[q * 4];
        f32x4 u = *(const f32x4*)&gA1[q * 4];
        *(f32x4*)&al[sra][sca + q * 4] = v + u;
      }
      int srb = t >> 4, scb = (t & 15) << 2;  // bl: 1 x f32x4 per thread
      *(f32x4*)&bl[srb][scb] = *(const f32x4*)(fwd + (size_t)(c0 + srb) * DMID + mbase + scb);
      if (t < MC) {                           // wl[m] = -2 * sum_s partial[s][m]
        float v = 0.f;
#pragma unroll
        for (int s = 0; s < 16; ++s) v += partial[(size_t)s * DMID + mbase + t];
        wl[t] = -2.f * v;
      }
    }
    __syncthreads();
    for (int mm = 0; mm < MC; mm += 4) {
      f32x4 wv = *(const f32x4*)&wl[mm];
      f32x4 bv = *(const f32x4*)&bl[ci][mm];
      f32x4 av0 = *(const f32x4*)&al[pi][mm];
      f32x4 av1 = *(const f32x4*)&al[pi + 16][mm];
      f32x4 av2 = *(const f32x4*)&al[pi + 32][mm];
      f32x4 av3 = *(const f32x4*)&al[pi + 48][mm];
#pragma unroll
      for (int u = 0; u < 4; ++u) {
        float w = wv[u], b = bv[u];
        float e0 = __builtin_amdgcn_exp2f(av0[u] * b);
        float e1 = __builtin_amdgcn_exp2f(av1[u] * b);
        float e2 = __builtin_amdgcn_exp2f(av2[u] * b);
        float e3 = __builtin_amdgcn_exp2f(av3[u] * b);
        acc[0] = fmaf(w, __builtin_amdgcn_rcpf(1.f + e0), acc[0]);
        acc[1] = fmaf(w, __builtin_amdgcn_rcpf(1.f + e1), acc[1]);
        acc[2] = fmaf(w, __builtin_amdgcn_rcpf(1.f + e2), acc[2]);
        acc[3] = fmaf(w, __builtin_amdgcn_rcpf(1.f + e3), acc[3]);
      }
    }
  }
  float* cp = coefp + (size_t)mz * (PN * NC);
#pragma unroll
  for (int j = 0; j < 4; ++j) {
    int p = p0 + pi + 16 * j;
    if (p < PN) cp[(size_t)p * NC + c0 + ci] = acc[j];
  }
}

// ---------------------------------------------------------------- softmax + pooling; sums 8 coef partials
__global__ __launch_bounds__(256) void k_pool(const float* __restrict__ coefp,
                                              const float* __restrict__ img,
                                              float* __restrict__ out) {
  __shared__ __align__(16) float wt[HWN][16];
  __shared__ float red[16][16];
  __shared__ float mxs[16], inv[16];
  int dc = blockIdx.x * 256, cg = blockIdx.y * 16, b = blockIdx.z;
  int t = threadIdx.x;
  for (int i = t; i < HWN * 4; i += 256) {
    int hw = i >> 2, j4 = (i & 3) << 2;
    size_t o = (size_t)(b * HWN + hw) * NC + cg + j4;
    f32x4 s = {0.f, 0.f, 0.f, 0.f};
#pragma unroll
    for (int z = 0; z < PART; ++z) s += *(const f32x4*)&coefp[o + (size_t)z * (PN * NC)];
    *(f32x4*)&wt[hw][j4] = s;
  }
  __syncthreads();
  int j = t & 15, g = t >> 4;
  float pm = -1e30f;
  for (int hw = g; hw < HWN; hw += 16) pm = fmaxf(pm, wt[hw][j]);
  red[g][j] = pm;
  __syncthreads();
  if (t < 16) {
    float m = red[0][t];
#pragma unroll
    for (int g2 = 1; g2 < 16; ++g2) m = fmaxf(m, red[g2][t]);
    mxs[t] = m;
  }
  __syncthreads();
  float mj = mxs[j], ps = 0.f;
  for (int hw = g; hw < HWN; hw += 16) {
    float e = __builtin_amdgcn_exp2f((wt[hw][j] - mj) * 1.4426950408889634f);
    wt[hw][j] = e;
    ps += e;
  }
  red[g][j] = ps;
  __syncthreads();
  if (t < 16) {
    float s = 0.f;
#pragma unroll
    for (int g2 = 0; g2 < 16; ++g2) s += red[g2][t];
    inv[t] = 1.f / s;
  }
  __syncthreads();
  float acc[16];
#pragma unroll
  for (int q = 0; q < 16; ++q) acc[q] = 0.f;
  const float* fpd = img + ((size_t)b * DIMG + dc + t) * HWN;
  for (int hw = 0; hw < HWN; ++hw) {
    float v = fpd[hw];
#pragma unroll
    for (int q = 0; q < 16; ++q) acc[q] = fmaf(wt[hw][q], v, acc[q]);
  }
#pragma unroll
  for (int q = 0; q < 16; ++q)
    out[((size_t)b * NC + cg + q) * DIMG + dc + t] = acc[q] * inv[q];
}

// ----------------------------------------------------------------
extern "C" void kernel_launch(void* const* d_in, const int* in_sizes, int n_in,
                              void* d_out, int out_size, void* d_ws, size_t ws_size,
                              hipStream_t stream) {
  const float* img  = (const float*)d_in[1];
  const float* word = (const float*)d_in[2];
  const float* W1   = (const float*)d_in[3];
  const float* W2   = (const float*)d_in[4];
  const float* W3   = (const float*)d_in[5];
  const float* Wa   = (const float*)d_in[7];
  // b3 (d_in[6]) and ba (d_in[8]) are softmax-shift-invariant -> dropped.
  float* out = (float*)d_out;
  char* ws = (char*)d_ws;

  unsigned short* fmapH   = (unsigned short*)(ws + 0);         // 1600*2048*2 = 6,553,600
  unsigned short* W1h     = (unsigned short*)(ws + 6553600);   // 1024*2048*2 = 4,194,304
  float*          fwhp    = (float*)(ws + 10747904);           // 2*1600*1024*4 = 13,107,200
  float*          fwd     = (float*)(ws + 23855104);           //  96*1024*4 =   393,216
  float*          partial = (float*)(ws + 24248320);           //  16*1024*4 =    65,536
  float*          coefp   = (float*)(ws + 24313856);           // 8*1568*80*4 = 4,014,080

  hipLaunchKernelGGL(k_tc, dim3(5632), dim3(32, 8), 0, stream, img, fmapH, W1, W1h);
  hipLaunchKernelGGL(k_fwdweff, dim3(144), dim3(256), 0, stream,
                     word, W2, fwd, Wa, W3, partial);
  hipLaunchKernelGGL(k_gemm, dim3(25, 16, 2), dim3(256), 0, stream, fmapH, W1h, fwhp);
  hipLaunchKernelGGL(k_coef, dim3(25, 5, 8), dim3(256), 0, stream, fwhp, fwd, partial, coefp);
  hipLaunchKernelGGL(k_pool, dim3(8, 5, 8), dim3(256), 0, stream, coefp, img, out);
  (void)in_sizes; (void)n_in; (void)out_size; (void)ws_size;
}

// Round 16
// 103.647 us; speedup vs baseline: 1.3509x; 1.0931x over previous
//
#include <hip/hip_runtime.h>
#include <hip/hip_bf16.h>
#include <stdint.h>

#define NB 8
#define DIMG 2048
#define HWN 196
#define PN 1568
#define DMID 1024
#define NC 80
#define DWORD 300
#define PART 8

typedef short bf16x8 __attribute__((ext_vector_type(8)));
typedef float f32x4 __attribute__((ext_vector_type(4)));

__device__ __forceinline__ unsigned short f2bf(float x) {
  union { float f; unsigned u; } c; c.f = x;
  unsigned r = c.u + 0x7FFFu + ((c.u >> 16) & 1u);
  return (unsigned short)(r >> 16);
}

// ---------------------------------------------------------------- transpose (64-d tiles, paired bf16 stores) + W1 cvt
__global__ void k_tc(const float* __restrict__ img, unsigned short* __restrict__ fmapH,
                     const float* __restrict__ W1, unsigned short* __restrict__ W1h) {
  __shared__ float tile[64][33];
  int bx = blockIdx.x;
  int tx = threadIdx.x, ty = threadIdx.y;
  if (bx < 1792) {
    int d0 = (bx & 31) * 64;           // 32 d-tiles
    int rem = bx >> 5;                 // 0..55
    int h0 = (rem % 7) * 32, b = rem / 7;
    const float* src = img + (size_t)b * DIMG * HWN;
#pragma unroll
    for (int i = 0; i < 64; i += 8) {
      int hw = h0 + tx;
      tile[ty + i][tx] = (hw < HWN) ? src[(size_t)(d0 + ty + i) * HWN + hw] : 0.f;
    }
    __syncthreads();
#pragma unroll
    for (int i = 0; i < 32; i += 8) {
      int hw = h0 + ty + i;
      if (hw < HWN) {
        int d = tx * 2;
        unsigned short lo = f2bf(tile[d][ty + i]);
        unsigned short hi = f2bf(tile[d + 1][ty + i]);
        unsigned v = (unsigned)lo | ((unsigned)hi << 16);
        *(unsigned*)&fmapH[(size_t)(b * HWN + hw) * DIMG + d0 + d] = v;
      }
    }
  } else {
    int tid = ty * 32 + tx;
    int i = ((bx - 1792) * 256 + tid) * 4;
    f32x4 v = *(const f32x4*)(W1 + i);
    ushort4 s;
    s.x = f2bf(v[0]); s.y = f2bf(v[1]); s.z = f2bf(v[2]); s.w = f2bf(v[3]);
    *(ushort4*)(W1h + i) = s;
  }
}

// ---------------------------------------------------------------- MERGED: gemm (K-split-2) + fwd + weff
// bz in [0,800)      : gemm  fwhp[kz][1600][1024] = fmapH[.][kz*1024:+1024] x W1h[.][...]^T
// bz in [800,1120)   : fwd[c][m] = SC * sum_k word[c][k]*W2[m][k]  (16c x 16m tiles)
// bz in [1120,1184)  : partial[s][m] n-chunked Wa @ W3
#define GLDS(g, l) \
  __builtin_amdgcn_global_load_lds((const __attribute__((address_space(1))) void*)(g), \
                                   (__attribute__((address_space(3))) void*)(l), 16, 0, 0)

__global__ __launch_bounds__(256) void k_gw(const unsigned short* __restrict__ A,
                                            const unsigned short* __restrict__ Bw,
                                            float* __restrict__ C,
                                            const float* __restrict__ word,
                                            const float* __restrict__ W2,
                                            float* __restrict__ fwd,
                                            const float* __restrict__ Wa,
                                            const float* __restrict__ W3,
                                            float* __restrict__ partial) {
  __shared__ __align__(16) char smem[49152];
  int bz = blockIdx.x;
  int t = threadIdx.x;
  if (bz < 800) {
    unsigned short* As = (unsigned short*)smem;          // [3][4096]
    unsigned short* Bs = As + 3 * 4096;                  // [3][4096]
    int m0 = (bz % 25) * 64;
    int n0 = ((bz / 25) & 15) * 64;
    int koff = (bz / 400) * 1024;
    int w = t >> 6, l = t & 63;
    int wr = w >> 1, wc = w & 1;
    f32x4 zero = {0.f, 0.f, 0.f, 0.f};
    f32x4 acc00 = zero, acc01 = zero, acc10 = zero, acc11 = zero;

    int r0 = t >> 3, c0 = t & 7;
    int r1 = r0 + 32;
    const unsigned short* ga0 = A + (size_t)(m0 + r0) * 2048 + koff + ((c0 ^ (r0 & 7)) << 3);
    const unsigned short* ga1 = A + (size_t)(m0 + r1) * 2048 + koff + ((c0 ^ (r1 & 7)) << 3);
    const unsigned short* gb0 = Bw + (size_t)(n0 + r0) * 2048 + koff + ((c0 ^ (r0 & 7)) << 3);
    const unsigned short* gb1 = Bw + (size_t)(n0 + r1) * 2048 + koff + ((c0 ^ (r1 & 7)) << 3);

    int ra = wr * 32 + (l & 15);
    int rb = wc * 32 + (l & 15);
    int cc = l >> 4;
    int a_k0 = ra * 64 + (((cc) ^ (ra & 7)) << 3);
    int a_k1 = ra * 64 + (((cc + 4) ^ (ra & 7)) << 3);
    int b_k0 = rb * 64 + (((cc) ^ (rb & 7)) << 3);
    int b_k1 = rb * 64 + (((cc + 4) ^ (rb & 7)) << 3);

#define STAGE(bi, kk) do { \
    GLDS(ga0 + (kk), As + (bi) * 4096 + t * 8); \
    GLDS(ga1 + (kk), As + (bi) * 4096 + t * 8 + 2048); \
    GLDS(gb0 + (kk), Bs + (bi) * 4096 + t * 8); \
    GLDS(gb1 + (kk), Bs + (bi) * 4096 + t * 8 + 2048); \
  } while (0)
#define COMPUTE(bi) do { \
    const unsigned short* ap = As + (bi) * 4096; \
    const unsigned short* bp = Bs + (bi) * 4096; \
    bf16x8 A0 = *(const bf16x8*)(ap + a_k0); \
    bf16x8 A1 = *(const bf16x8*)(ap + a_k0 + 1024); \
    bf16x8 B0 = *(const bf16x8*)(bp + b_k0); \
    bf16x8 B1 = *(const bf16x8*)(bp + b_k0 + 1024); \
    acc00 = __builtin_amdgcn_mfma_f32_16x16x32_bf16(A0, B0, acc00, 0, 0, 0); \
    acc01 = __builtin_amdgcn_mfma_f32_16x16x32_bf16(A0, B1, acc01, 0, 0, 0); \
    acc10 = __builtin_amdgcn_mfma_f32_16x16x32_bf16(A1, B0, acc10, 0, 0, 0); \
    acc11 = __builtin_amdgcn_mfma_f32_16x16x32_bf16(A1, B1, acc11, 0, 0, 0); \
    bf16x8 A2 = *(const bf16x8*)(ap + a_k1); \
    bf16x8 A3 = *(const bf16x8*)(ap + a_k1 + 1024); \
    bf16x8 B2 = *(const bf16x8*)(bp + b_k1); \
    bf16x8 B3 = *(const bf16x8*)(bp + b_k1 + 1024); \
    acc00 = __builtin_amdgcn_mfma_f32_16x16x32_bf16(A2, B2, acc00, 0, 0, 0); \
    acc01 = __builtin_amdgcn_mfma_f32_16x16x32_bf16(A2, B3, acc01, 0, 0, 0); \
    acc10 = __builtin_amdgcn_mfma_f32_16x16x32_bf16(A3, B2, acc10, 0, 0, 0); \
    acc11 = __builtin_amdgcn_mfma_f32_16x16x32_bf16(A3, B3, acc11, 0, 0, 0); \
  } while (0)

    STAGE(0, 0);
    STAGE(1, 64);
    asm volatile("s_waitcnt vmcnt(4)" ::: "memory");
    __builtin_amdgcn_s_barrier();
    __builtin_amdgcn_sched_barrier(0);
    for (int kt = 0; kt < 16; ++kt) {
      int cur = kt % 3;
      if (kt < 14) STAGE((kt + 2) % 3, (kt + 2) * 64);
      COMPUTE(cur);
      if (kt < 14) {
        asm volatile("s_waitcnt vmcnt(4)" ::: "memory");
        __builtin_amdgcn_s_barrier();
        __builtin_amdgcn_sched_barrier(0);
      } else if (kt == 14) {
        asm volatile("s_waitcnt vmcnt(0)" ::: "memory");
        __builtin_amdgcn_s_barrier();
        __builtin_amdgcn_sched_barrier(0);
      }
    }
    float* Cz = C + (size_t)(bz / 400) * (1600 * DMID);
    int cr = (l >> 4) << 2, ccn = l & 15;
#pragma unroll
    for (int q = 0; q < 4; ++q) {
      Cz[(size_t)(m0 + wr * 32 + cr + q) * DMID + n0 + wc * 32 + ccn] = acc00[q];
      Cz[(size_t)(m0 + wr * 32 + cr + q) * DMID + n0 + wc * 32 + 16 + ccn] = acc01[q];
      Cz[(size_t)(m0 + wr * 32 + 16 + cr + q) * DMID + n0 + wc * 32 + ccn] = acc10[q];
      Cz[(size_t)(m0 + wr * 32 + 16 + cr + q) * DMID + n0 + wc * 32 + 16 + ccn] = acc11[q];
    }
#undef STAGE
#undef COMPUTE
  } else if (bz < 1120) {
    float* w2s = (float*)smem;            // [16][300] 19.2 KB
    float* wds = w2s + 16 * 300;          // [16][300] 19.2 KB
    int idx = bz - 800;
    int m0 = (idx & 63) * 16, c0 = (idx >> 6) * 16;
    const float SC = 2.8853900817779268f;  // 2*log2(e)
    for (int u = t; u < 16 * 75; u += 256) {
      int r = u / 75, q = u - r * 75;
      *(f32x4*)&w2s[r * 300 + q * 4] = *(const f32x4*)(W2 + (size_t)(m0 + r) * DWORD + q * 4);
      f32x4 v = *(const f32x4*)(word + (size_t)(c0 + r) * DWORD + q * 4);
      *(f32x4*)&wds[r * 300 + q * 4] = v * SC;
    }
    __syncthreads();
    int ci = t >> 4, mi = t & 15;
    f32x4 av = {0.f, 0.f, 0.f, 0.f};
    const float* wr_ = &wds[ci * 300];
    const float* w2r = &w2s[mi * 300];
    for (int q = 0; q < 75; ++q) {
      f32x4 wv = *(const f32x4*)&wr_[q * 4];
      f32x4 bv = *(const f32x4*)&w2r[q * 4];
#pragma unroll
      for (int u = 0; u < 4; ++u) av[u] = fmaf(wv[u], bv[u], av[u]);
    }
    fwd[(size_t)(c0 + ci) * DMID + m0 + mi] = av[0] + av[1] + av[2] + av[3];
  } else {
    int idx = bz - 1120;
    int m = (idx & 3) * 256 + t;
    int n0 = (idx >> 2) * 64;
    float acc = 0.f;
    for (int n = n0; n < n0 + 64; ++n) acc = fmaf(Wa[n], W3[(size_t)n * DMID + m], acc);
    partial[(size_t)(idx >> 2) * DMID + m] = acc;
  }
}

// ---------------------------------------------------------------- coef logits: 32p x 16c x 128m, sums 2 fwh K-halves
// grid (49, 5, 8) = 1960 blocks, 13.3 KB LDS -> fully resident, ~30 waves/CU
#define MC 64
__global__ __launch_bounds__(256) void k_coef(const float* __restrict__ fwhp,
                                              const float* __restrict__ fwd,
                                              const float* __restrict__ partial,
                                              float* __restrict__ coefp) {
  __shared__ __align__(16) float al[32][68];   // 8.7 KB
  __shared__ __align__(16) float bl[16][68];   // 4.3 KB
  __shared__ __align__(16) float wl[MC];
  int p0 = blockIdx.x * 32, c0 = blockIdx.y * 16, mz = blockIdx.z;
  int t = threadIdx.x;
  int pi = t >> 4, ci = t & 15;
  float acc[2] = {0.f, 0.f};
  const float* fwh0 = fwhp;
  const float* fwh1 = fwhp + (size_t)1600 * DMID;

  for (int mc = 0; mc < 2; ++mc) {
    int mbase = mz * 128 + mc * MC;
    __syncthreads();
    {
      int sra = t >> 3, sca = (t & 7) << 3;   // al: 2 x f32x4 per thread
      const float* gA0 = fwh0 + (size_t)(p0 + sra) * DMID + mbase + sca;
      const float* gA1 = fwh1 + (size_t)(p0 + sra) * DMID + mbase + sca;
#pragma unroll
      for (int q = 0; q < 2; ++q) {
        f32x4 v = *(const f32x4*)&gA0[q * 4];
        f32x4 u = *(const f32x4*)&gA1[q * 4];
        *(f32x4*)&al[sra][sca + q * 4] = v + u;
      }
      int srb = t >> 4, scb = (t & 15) << 2;  // bl: 1 x f32x4 per thread
      *(f32x4*)&bl[srb][scb] = *(const f32x4*)(fwd + (size_t)(c0 + srb) * DMID + mbase + scb);
      if (t < MC) {
        float v = 0.f;
#pragma unroll
        for (int s = 0; s < 16; ++s) v += partial[(size_t)s * DMID + mbase + t];
        wl[t] = -2.f * v;
      }
    }
    __syncthreads();
    for (int mm = 0; mm < MC; mm += 4) {
      f32x4 wv = *(const f32x4*)&wl[mm];
      f32x4 bv = *(const f32x4*)&bl[ci][mm];
      f32x4 av0 = *(const f32x4*)&al[pi][mm];
      f32x4 av1 = *(const f32x4*)&al[pi + 16][mm];
#pragma unroll
      for (int u = 0; u < 4; ++u) {
        float w = wv[u], b = bv[u];
        float e0 = __builtin_amdgcn_exp2f(av0[u] * b);
        float e1 = __builtin_amdgcn_exp2f(av1[u] * b);
        acc[0] = fmaf(w, __builtin_amdgcn_rcpf(1.f + e0), acc[0]);
        acc[1] = fmaf(w, __builtin_amdgcn_rcpf(1.f + e1), acc[1]);
      }
    }
  }
  float* cp = coefp + (size_t)mz * (PN * NC);
#pragma unroll
  for (int j = 0; j < 2; ++j) {
    int p = p0 + pi + 16 * j;
    if (p < PN) cp[(size_t)p * NC + c0 + ci] = acc[j];
  }
}

// ---------------------------------------------------------------- softmax + pooling; sums 8 coef partials
__global__ __launch_bounds__(256) void k_pool(const float* __restrict__ coefp,
                                              const float* __restrict__ img,
                                              float* __restrict__ out) {
  __shared__ __align__(16) float wt[HWN][16];
  __shared__ float red[16][16];
  __shared__ float mxs[16], inv[16];
  int dc = blockIdx.x * 256, cg = blockIdx.y * 16, b = blockIdx.z;
  int t = threadIdx.x;
  for (int i = t; i < HWN * 4; i += 256) {
    int hw = i >> 2, j4 = (i & 3) << 2;
    size_t o = (size_t)(b * HWN + hw) * NC + cg + j4;
    f32x4 s = {0.f, 0.f, 0.f, 0.f};
#pragma unroll
    for (int z = 0; z < PART; ++z) s += *(const f32x4*)&coefp[o + (size_t)z * (PN * NC)];
    *(f32x4*)&wt[hw][j4] = s;
  }
  __syncthreads();
  int j = t & 15, g = t >> 4;
  float pm = -1e30f;
  for (int hw = g; hw < HWN; hw += 16) pm = fmaxf(pm, wt[hw][j]);
  red[g][j] = pm;
  __syncthreads();
  if (t < 16) {
    float m = red[0][t];
#pragma unroll
    for (int g2 = 1; g2 < 16; ++g2) m = fmaxf(m, red[g2][t]);
    mxs[t] = m;
  }
  __syncthreads();
  float mj = mxs[j], ps = 0.f;
  for (int hw = g; hw < HWN; hw += 16) {
    float e = __builtin_amdgcn_exp2f((wt[hw][j] - mj) * 1.4426950408889634f);
    wt[hw][j] = e;
    ps += e;
  }
  red[g][j] = ps;
  __syncthreads();
  if (t < 16) {
    float s = 0.f;
#pragma unroll
    for (int g2 = 0; g2 < 16; ++g2) s += red[g2][t];
    inv[t] = 1.f / s;
  }
  __syncthreads();
  float acc[16];
#pragma unroll
  for (int q = 0; q < 16; ++q) acc[q] = 0.f;
  const float* fpd = img + ((size_t)b * DIMG + dc + t) * HWN;
  for (int hw = 0; hw < HWN; ++hw) {
    float v = fpd[hw];
#pragma unroll
    for (int q = 0; q < 16; ++q) acc[q] = fmaf(wt[hw][q], v, acc[q]);
  }
#pragma unroll
  for (int q = 0; q < 16; ++q)
    out[((size_t)b * NC + cg + q) * DIMG + dc + t] = acc[q] * inv[q];
}

// ----------------------------------------------------------------
extern "C" void kernel_launch(void* const* d_in, const int* in_sizes, int n_in,
                              void* d_out, int out_size, void* d_ws, size_t ws_size,
                              hipStream_t stream) {
  const float* img  = (const float*)d_in[1];
  const float* word = (const float*)d_in[2];
  const float* W1   = (const float*)d_in[3];
  const float* W2   = (const float*)d_in[4];
  const float* W3   = (const float*)d_in[5];
  const float* Wa   = (const float*)d_in[7];
  // b3 (d_in[6]) and ba (d_in[8]) are softmax-shift-invariant -> dropped.
  float* out = (float*)d_out;
  char* ws = (char*)d_ws;

  unsigned short* fmapH   = (unsigned short*)(ws + 0);         // 1600*2048*2 = 6,553,600
  unsigned short* W1h     = (unsigned short*)(ws + 6553600);   // 1024*2048*2 = 4,194,304
  float*          fwhp    = (float*)(ws + 10747904);           // 2*1600*1024*4 = 13,107,200
  float*          fwd     = (float*)(ws + 23855104);           //  96*1024*4 =   393,216
  float*          partial = (float*)(ws + 24248320);           //  16*1024*4 =    65,536
  float*          coefp   = (float*)(ws + 24313856);           // 8*1568*80*4 = 4,014,080

  hipLaunchKernelGGL(k_tc, dim3(3840), dim3(32, 8), 0, stream, img, fmapH, W1, W1h);
  hipLaunchKernelGGL(k_gw, dim3(1184), dim3(256), 0, stream,
                     fmapH, W1h, fwhp, word, W2, fwd, Wa, W3, partial);
  hipLaunchKernelGGL(k_coef, dim3(49, 5, 8), dim3(256), 0, stream, fwhp, fwd, partial, coefp);
  hipLaunchKernelGGL(k_pool, dim3(8, 5, 8), dim3(256), 0, stream, coefp, img, out);
  (void)in_sizes; (void)n_in; (void)out_size; (void)ws_size;
}

// Round 17
// 100.159 us; speedup vs baseline: 1.3980x; 1.0348x over previous
//
#include <hip/hip_runtime.h>
#include <hip/hip_bf16.h>
#include <stdint.h>

#define NB 8
#define DIMG 2048
#define HWN 196
#define PN 1568
#define DMID 1024
#define NC 80
#define DWORD 300
#define PART 8
#define KSPLIT 4

typedef short bf16x8 __attribute__((ext_vector_type(8)));
typedef float f32x4 __attribute__((ext_vector_type(4)));

__device__ __forceinline__ unsigned short f2bf(float x) {
  union { float f; unsigned u; } c; c.f = x;
  unsigned r = c.u + 0x7FFFu + ((c.u >> 16) & 1u);
  return (unsigned short)(r >> 16);
}

// ---------------------------------------------------------------- transpose (64-d tiles, paired bf16 stores) + W1 cvt
__global__ void k_tc(const float* __restrict__ img, unsigned short* __restrict__ fmapH,
                     const float* __restrict__ W1, unsigned short* __restrict__ W1h) {
  __shared__ float tile[64][33];
  int bx = blockIdx.x;
  int tx = threadIdx.x, ty = threadIdx.y;
  if (bx < 1792) {
    int d0 = (bx & 31) * 64;           // 32 d-tiles
    int rem = bx >> 5;                 // 0..55
    int h0 = (rem % 7) * 32, b = rem / 7;
    const float* src = img + (size_t)b * DIMG * HWN;
#pragma unroll
    for (int i = 0; i < 64; i += 8) {
      int hw = h0 + tx;
      tile[ty + i][tx] = (hw < HWN) ? src[(size_t)(d0 + ty + i) * HWN + hw] : 0.f;
    }
    __syncthreads();
#pragma unroll
    for (int i = 0; i < 32; i += 8) {
      int hw = h0 + ty + i;
      if (hw < HWN) {
        int d = tx * 2;
        unsigned short lo = f2bf(tile[d][ty + i]);
        unsigned short hi = f2bf(tile[d + 1][ty + i]);
        unsigned v = (unsigned)lo | ((unsigned)hi << 16);
        *(unsigned*)&fmapH[(size_t)(b * HWN + hw) * DIMG + d0 + d] = v;
      }
    }
  } else {
    int tid = ty * 32 + tx;
    int i = ((bx - 1792) * 256 + tid) * 4;
    f32x4 v = *(const f32x4*)(W1 + i);
    ushort4 s;
    s.x = f2bf(v[0]); s.y = f2bf(v[1]); s.z = f2bf(v[2]); s.w = f2bf(v[3]);
    *(ushort4*)(W1h + i) = s;
  }
}

// ---------------------------------------------------------------- MERGED: gemm (128^2 tile, K-split-4) + fwd + weff
// bz in [0,416)   : gemm  fwhp[kz][1600][1024] partial over K-chunk kz*512
// bz in [416,736) : fwd[c][m] = SC * sum_k word[c][k]*W2[m][k]  (16c x 16m tiles)
// bz in [736,800) : partial[s][m] n-chunked Wa @ W3
#define GLDS(g, l) \
  __builtin_amdgcn_global_load_lds((const __attribute__((address_space(1))) void*)(g), \
                                   (__attribute__((address_space(3))) void*)(l), 16, 0, 0)

__global__ __launch_bounds__(256) void k_gw(const unsigned short* __restrict__ A,
                                            const unsigned short* __restrict__ Bw,
                                            float* __restrict__ C,
                                            const float* __restrict__ word,
                                            const float* __restrict__ W2,
                                            float* __restrict__ fwd,
                                            const float* __restrict__ Wa,
                                            const float* __restrict__ W3,
                                            float* __restrict__ partial) {
  __shared__ __align__(16) char smem[38400];
  int bz = blockIdx.x;
  int t = threadIdx.x;
  if (bz < 416) {
    unsigned short* As = (unsigned short*)smem;          // [128*32] = 8 KB
    unsigned short* Bs = As + 4096;                      // [128*32] = 8 KB
    int m0 = (bz % 13) * 128;
    int n0 = ((bz / 13) & 7) * 128;
    int koff = (bz / 104) * 512;
    int w = t >> 6, l = t & 63;
    int wr = w >> 1, wc = w & 1;                          // wave tile 64x64
    f32x4 zero = {0.f, 0.f, 0.f, 0.f};
    f32x4 acc[4][4];
#pragma unroll
    for (int i = 0; i < 4; ++i)
#pragma unroll
      for (int j = 0; j < 4; ++j) acc[i][j] = zero;

    int sr = t >> 2, sk = (t & 3) << 3;                   // 512 chunks/matrix, 2 per thread
    const unsigned short* ga0 = A + (size_t)(m0 + sr) * 2048 + koff + sk;
    const unsigned short* ga1 = A + (size_t)(m0 + 64 + sr) * 2048 + koff + sk;
    const unsigned short* gb0 = Bw + (size_t)(n0 + sr) * 2048 + koff + sk;
    const unsigned short* gb1 = Bw + (size_t)(n0 + 64 + sr) * 2048 + koff + sk;

    int fr = l & 15, ko = (l >> 4) << 3;

    for (int kk = 0; kk < 512; kk += 32) {
      __syncthreads();
      GLDS(ga0 + kk, As + t * 8);
      GLDS(ga1 + kk, As + t * 8 + 2048);
      GLDS(gb0 + kk, Bs + t * 8);
      GLDS(gb1 + kk, Bs + t * 8 + 2048);
      __syncthreads();
      bf16x8 a[4], b[4];
#pragma unroll
      for (int i = 0; i < 4; ++i)
        a[i] = *(const bf16x8*)&As[(wr * 64 + i * 16 + fr) * 32 + ko];
#pragma unroll
      for (int j = 0; j < 4; ++j)
        b[j] = *(const bf16x8*)&Bs[(wc * 64 + j * 16 + fr) * 32 + ko];
#pragma unroll
      for (int i = 0; i < 4; ++i)
#pragma unroll
        for (int j = 0; j < 4; ++j)
          acc[i][j] = __builtin_amdgcn_mfma_f32_16x16x32_bf16(a[i], b[j], acc[i][j], 0, 0, 0);
    }
    float* Cz = C + (size_t)(bz / 104) * (1600 * DMID);
    int cr = (l >> 4) << 2, cc2 = l & 15;
#pragma unroll
    for (int i = 0; i < 4; ++i) {
#pragma unroll
      for (int q = 0; q < 4; ++q) {
        int row = m0 + wr * 64 + i * 16 + cr + q;
        if (row < 1600) {
#pragma unroll
          for (int j = 0; j < 4; ++j)
            Cz[(size_t)row * DMID + n0 + wc * 64 + j * 16 + cc2] = acc[i][j][q];
        }
      }
    }
  } else if (bz < 736) {
    float* w2s = (float*)smem;            // [16][300] 19.2 KB
    float* wds = w2s + 16 * 300;          // [16][300] 19.2 KB
    int idx = bz - 416;
    int m0 = (idx & 63) * 16, c0 = (idx >> 6) * 16;
    const float SC = 2.8853900817779268f;  // 2*log2(e)
    for (int u = t; u < 16 * 75; u += 256) {
      int r = u / 75, q = u - r * 75;
      *(f32x4*)&w2s[r * 300 + q * 4] = *(const f32x4*)(W2 + (size_t)(m0 + r) * DWORD + q * 4);
      f32x4 v = *(const f32x4*)(word + (size_t)(c0 + r) * DWORD + q * 4);
      *(f32x4*)&wds[r * 300 + q * 4] = v * SC;
    }
    __syncthreads();
    int ci = t >> 4, mi = t & 15;
    f32x4 av = {0.f, 0.f, 0.f, 0.f};
    const float* wr_ = &wds[ci * 300];
    const float* w2r = &w2s[mi * 300];
    for (int q = 0; q < 75; ++q) {
      f32x4 wv = *(const f32x4*)&wr_[q * 4];
      f32x4 bv = *(const f32x4*)&w2r[q * 4];
#pragma unroll
      for (int u = 0; u < 4; ++u) av[u] = fmaf(wv[u], bv[u], av[u]);
    }
    fwd[(size_t)(c0 + ci) * DMID + m0 + mi] = av[0] + av[1] + av[2] + av[3];
  } else {
    int idx = bz - 736;
    int m = (idx & 3) * 256 + t;
    int n0 = (idx >> 2) * 64;
    float acc = 0.f;
#pragma unroll 4
    for (int n = n0; n < n0 + 64; ++n) acc = fmaf(Wa[n], W3[(size_t)n * DMID + m], acc);
    partial[(size_t)(idx >> 2) * DMID + m] = acc;
  }
}

// ---------------------------------------------------------------- coef logits: 32p x 16c x 128m, sums 4 fwh K-parts
#define MC 64
__global__ __launch_bounds__(256) void k_coef(const float* __restrict__ fwhp,
                                              const float* __restrict__ fwd,
                                              const float* __restrict__ partial,
                                              float* __restrict__ coefp) {
  __shared__ __align__(16) float al[32][68];   // 8.7 KB
  __shared__ __align__(16) float bl[16][68];   // 4.3 KB
  __shared__ __align__(16) float wl[MC];
  int p0 = blockIdx.x * 32, c0 = blockIdx.y * 16, mz = blockIdx.z;
  int t = threadIdx.x;
  int pi = t >> 4, ci = t & 15;
  float acc[2] = {0.f, 0.f};
  const size_t FS = (size_t)1600 * DMID;

  for (int mc = 0; mc < 2; ++mc) {
    int mbase = mz * 128 + mc * MC;
    __syncthreads();
    {
      int sra = t >> 3, sca = (t & 7) << 3;   // al: 2 x f32x4 per thread
      const float* gA = fwhp + (size_t)(p0 + sra) * DMID + mbase + sca;
#pragma unroll
      for (int q = 0; q < 2; ++q) {
        f32x4 v = *(const f32x4*)&gA[q * 4];
        v += *(const f32x4*)&gA[FS + q * 4];
        v += *(const f32x4*)&gA[2 * FS + q * 4];
        v += *(const f32x4*)&gA[3 * FS + q * 4];
        *(f32x4*)&al[sra][sca + q * 4] = v;
      }
      int srb = t >> 4, scb = (t & 15) << 2;  // bl: 1 x f32x4 per thread
      *(f32x4*)&bl[srb][scb] = *(const f32x4*)(fwd + (size_t)(c0 + srb) * DMID + mbase + scb);
      if (t < MC) {
        float v = 0.f;
#pragma unroll
        for (int s = 0; s < 16; ++s) v += partial[(size_t)s * DMID + mbase + t];
        wl[t] = -2.f * v;
      }
    }
    __syncthreads();
    for (int mm = 0; mm < MC; mm += 4) {
      f32x4 wv = *(const f32x4*)&wl[mm];
      f32x4 bv = *(const f32x4*)&bl[ci][mm];
      f32x4 av0 = *(const f32x4*)&al[pi][mm];
      f32x4 av1 = *(const f32x4*)&al[pi + 16][mm];
#pragma unroll
      for (int u = 0; u < 4; ++u) {
        float w = wv[u], b = bv[u];
        float e0 = __builtin_amdgcn_exp2f(av0[u] * b);
        float e1 = __builtin_amdgcn_exp2f(av1[u] * b);
        acc[0] = fmaf(w, __builtin_amdgcn_rcpf(1.f + e0), acc[0]);
        acc[1] = fmaf(w, __builtin_amdgcn_rcpf(1.f + e1), acc[1]);
      }
    }
  }
  float* cp = coefp + (size_t)mz * (PN * NC);
#pragma unroll
  for (int j = 0; j < 2; ++j) {
    int p = p0 + pi + 16 * j;
    if (p < PN) cp[(size_t)p * NC + c0 + ci] = acc[j];
  }
}

// ---------------------------------------------------------------- softmax + pooling; sums 8 coef partials
__global__ __launch_bounds__(256) void k_pool(const float* __restrict__ coefp,
                                              const float* __restrict__ img,
                                              float* __restrict__ out) {
  __shared__ __align__(16) float wt[HWN][16];
  __shared__ float red[16][16];
  __shared__ float mxs[16], inv[16];
  int dc = blockIdx.x * 256, cg = blockIdx.y * 16, b = blockIdx.z;
  int t = threadIdx.x;
  for (int i = t; i < HWN * 4; i += 256) {
    int hw = i >> 2, j4 = (i & 3) << 2;
    size_t o = (size_t)(b * HWN + hw) * NC + cg + j4;
    f32x4 s = {0.f, 0.f, 0.f, 0.f};
#pragma unroll
    for (int z = 0; z < PART; ++z) s += *(const f32x4*)&coefp[o + (size_t)z * (PN * NC)];
    *(f32x4*)&wt[hw][j4] = s;
  }
  __syncthreads();
  int j = t & 15, g = t >> 4;
  float pm = -1e30f;
  for (int hw = g; hw < HWN; hw += 16) pm = fmaxf(pm, wt[hw][j]);
  red[g][j] = pm;
  __syncthreads();
  if (t < 16) {
    float m = red[0][t];
#pragma unroll
    for (int g2 = 1; g2 < 16; ++g2) m = fmaxf(m, red[g2][t]);
    mxs[t] = m;
  }
  __syncthreads();
  float mj = mxs[j], ps = 0.f;
  for (int hw = g; hw < HWN; hw += 16) {
    float e = __builtin_amdgcn_exp2f((wt[hw][j] - mj) * 1.4426950408889634f);
    wt[hw][j] = e;
    ps += e;
  }
  red[g][j] = ps;
  __syncthreads();
  if (t < 16) {
    float s = 0.f;
#pragma unroll
    for (int g2 = 0; g2 < 16; ++g2) s += red[g2][t];
    inv[t] = 1.f / s;
  }
  __syncthreads();
  float acc[16];
#pragma unroll
  for (int q = 0; q < 16; ++q) acc[q] = 0.f;
  const float* fpd = img + ((size_t)b * DIMG + dc + t) * HWN;
  for (int hw = 0; hw < HWN; ++hw) {
    float v = fpd[hw];
#pragma unroll
    for (int q = 0; q < 16; ++q) acc[q] = fmaf(wt[hw][q], v, acc[q]);
  }
#pragma unroll
  for (int q = 0; q < 16; ++q)
    out[((size_t)b * NC + cg + q) * DIMG + dc + t] = acc[q] * inv[q];
}

// ----------------------------------------------------------------
extern "C" void kernel_launch(void* const* d_in, const int* in_sizes, int n_in,
                              void* d_out, int out_size, void* d_ws, size_t ws_size,
                              hipStream_t stream) {
  const float* img  = (const float*)d_in[1];
  const float* word = (const float*)d_in[2];
  const float* W1   = (const float*)d_in[3];
  const float* W2   = (const float*)d_in[4];
  const float* W3   = (const float*)d_in[5];
  const float* Wa   = (const float*)d_in[7];
  // b3 (d_in[6]) and ba (d_in[8]) are softmax-shift-invariant -> dropped.
  float* out = (float*)d_out;
  char* ws = (char*)d_ws;

  unsigned short* fmapH   = (unsigned short*)(ws + 0);         // 1664*2048*2 = 6,815,744 (rows 1568+ stale, finite)
  unsigned short* W1h     = (unsigned short*)(ws + 6815744);   // 1024*2048*2 = 4,194,304
  float*          fwhp    = (float*)(ws + 11010048);           // 4*1600*1024*4 = 26,214,400
  float*          fwd     = (float*)(ws + 37224448);           //  96*1024*4 =   393,216
  float*          partial = (float*)(ws + 37617664);           //  16*1024*4 =    65,536
  float*          coefp   = (float*)(ws + 37683200);           // 8*1568*80*4 = 4,014,080

  hipLaunchKernelGGL(k_tc, dim3(3840), dim3(32, 8), 0, stream, img, fmapH, W1, W1h);
  hipLaunchKernelGGL(k_gw, dim3(800), dim3(256), 0, stream,
                     fmapH, W1h, fwhp, word, W2, fwd, Wa, W3, partial);
  hipLaunchKernelGGL(k_coef, dim3(49, 5, 8), dim3(256), 0, stream, fwhp, fwd, partial, coefp);
  hipLaunchKernelGGL(k_pool, dim3(8, 5, 8), dim3(256), 0, stream, coefp, img, out);
  (void)in_sizes; (void)n_in; (void)out_size; (void)ws_size;
}